// Round 16
// baseline (534.072 us; speedup 1.0000x reference)
//
#include <hip/hip_runtime.h>
#include <math.h>

#define N_NODES 50000
#define N_EDGES 1600000
#define IN_CH   512
#define OUT_CH  48
#define XW_LD   64                   // xw row stride in ushorts -> 128B, one cache line
#define N_TILES (N_NODES / 16)       // 3125 row-tiles, exact

#define BSHIFT  5                    // 32 nodes per bucket
#define BNODES  32
#define NB      ((N_NODES + BNODES - 1) / BNODES)   // 1563 buckets
#define ETILE   8192                 // edges per bin_edges block

#define BFRAG_SHORTS (16 * 3 * 64 * 8)   // 24576 shorts = 48 KB fragment image of B
#define GEMM_BLOCKS ((N_TILES + 3) / 4)  // 782
#define HIST_BLOCKS 256

typedef __attribute__((ext_vector_type(8))) short bf16x8;
typedef __attribute__((ext_vector_type(4))) float f32x4;

// fp32 -> bf16 (round-to-nearest-even), branch-free
static __device__ inline short f2bf(float x) {
    union { float f; unsigned u; } in; in.f = x;
    unsigned r = in.u + 0x7fffu + ((in.u >> 16) & 1u);
    return (short)(r >> 16);
}
static __device__ inline float bf2f(unsigned v16) {
    union { unsigned u; float f; } o; o.u = v16 << 16; return o.f;
}

// ---------------- Kernel 0: pre-format B into MFMA fragment layout (once) ----------------
__global__ __launch_bounds__(256) void prep_bfrag(const float* __restrict__ w,
                                                  unsigned short* __restrict__ wfrag) {
    int i = blockIdx.x * blockDim.x + threadIdx.x;       // one float4 per thread
    if (i >= IN_CH * OUT_CH / 4) return;
    int flat = i * 4;
    int k   = flat / OUT_CH;
    int col = flat % OUT_CH;
    float4 v = *reinterpret_cast<const float4*>(w + flat);
    int s = k >> 5, j = k & 7, q = (k >> 3) & 3;
    float vv[4] = {v.x, v.y, v.z, v.w};
    #pragma unroll
    for (int c = 0; c < 4; ++c) {
        int cc = col + c;
        int t  = cc >> 4;
        int ln = (cc & 15) | (q << 4);
        wfrag[((s * 3 + t) * 64 + ln) * 8 + j] = (unsigned short)f2bf(vv[c]);
    }
}

// ---------------- Kernel 1 (merged): gemm blocks + hist blocks ----------------
static __device__ void gemm_body(char* smem, const float* __restrict__ f,
                                 const unsigned short* __restrict__ wfrag,
                                 unsigned short* __restrict__ xw) {
    short* sBl = reinterpret_cast<short*>(smem);

    int tid  = threadIdx.x;
    int lane = tid & 63;
    int wid  = tid >> 6;

    {
        const uint4* gw = reinterpret_cast<const uint4*>(wfrag);
        uint4*       sw = reinterpret_cast<uint4*>(smem);
        #pragma unroll
        for (int i = 0; i < BFRAG_SHORTS / 8 / 256; ++i)   // 12 iterations
            sw[i * 256 + tid] = gw[i * 256 + tid];
    }
    __syncthreads();

    int tile = blockIdx.x * 4 + wid;
    if (tile >= N_TILES) return;

    const bf16x8* sB = reinterpret_cast<const bf16x8*>(sBl);

    int row = tile * 16 + (lane & 15);
    const float* fp = f + (size_t)row * IN_CH + ((lane >> 4) << 3);

    f32x4 acc0 = {0.f, 0.f, 0.f, 0.f};
    f32x4 acc1 = {0.f, 0.f, 0.f, 0.f};
    f32x4 acc2 = {0.f, 0.f, 0.f, 0.f};

    float4 a0[2], a1[2];
    a0[0] = *reinterpret_cast<const float4*>(fp);
    a1[0] = *reinterpret_cast<const float4*>(fp + 4);

    #pragma unroll
    for (int s = 0; s < 16; ++s) {
        const int cb = s & 1, nb = cb ^ 1;
        if (s + 1 < 16) {                                  // prefetch next K-step
            a0[nb] = *reinterpret_cast<const float4*>(fp + (s + 1) * 32);
            a1[nb] = *reinterpret_cast<const float4*>(fp + (s + 1) * 32 + 4);
        }
        bf16x8 a;
        a[0] = f2bf(a0[cb].x); a[1] = f2bf(a0[cb].y);
        a[2] = f2bf(a0[cb].z); a[3] = f2bf(a0[cb].w);
        a[4] = f2bf(a1[cb].x); a[5] = f2bf(a1[cb].y);
        a[6] = f2bf(a1[cb].z); a[7] = f2bf(a1[cb].w);
        bf16x8 b0 = sB[(s * 3 + 0) * 64 + lane];
        bf16x8 b1 = sB[(s * 3 + 1) * 64 + lane];
        bf16x8 b2 = sB[(s * 3 + 2) * 64 + lane];
        acc0 = __builtin_amdgcn_mfma_f32_16x16x32_bf16(a, b0, acc0, 0, 0, 0);
        acc1 = __builtin_amdgcn_mfma_f32_16x16x32_bf16(a, b1, acc1, 0, 0, 0);
        acc2 = __builtin_amdgcn_mfma_f32_16x16x32_bf16(a, b2, acc2, 0, 0, 0);
    }

    unsigned short* orow = xw + (size_t)tile * 16 * XW_LD;
    int c  = lane & 15;
    int r0 = (lane >> 4) * 4;
    #pragma unroll
    for (int r = 0; r < 4; ++r) {
        orow[(size_t)(r0 + r) * XW_LD +  0 + c] = (unsigned short)f2bf(acc0[r]);
        orow[(size_t)(r0 + r) * XW_LD + 16 + c] = (unsigned short)f2bf(acc1[r]);
        orow[(size_t)(r0 + r) * XW_LD + 32 + c] = (unsigned short)f2bf(acc2[r]);
    }
}

static __device__ void hist_body(char* smem, int bid, const int* __restrict__ dst,
                                 int* __restrict__ counts) {
    int* hc = reinterpret_cast<int*>(smem);
    for (int i = threadIdx.x; i < NB; i += 256) hc[i] = 0;
    __syncthreads();
    for (int e = bid * 256 + threadIdx.x; e < N_EDGES; e += HIST_BLOCKS * 256)
        atomicAdd(&hc[dst[e] >> BSHIFT], 1);
    __syncthreads();
    for (int i = threadIdx.x; i < NB; i += 256)
        if (hc[i]) atomicAdd(&counts[i], hc[i]);
}

__global__ __launch_bounds__(256) void gemm_hist(const float* __restrict__ f,
                                                 const unsigned short* __restrict__ wfrag,
                                                 unsigned short* __restrict__ xw,
                                                 const int* __restrict__ dst,
                                                 int* __restrict__ counts) {
    __shared__ __align__(16) char smem[BFRAG_SHORTS * 2];   // 48 KB union
    if (blockIdx.x < GEMM_BLOCKS) gemm_body(smem, f, wfrag, xw);
    else                          hist_body(smem, blockIdx.x - GEMM_BLOCKS, dst, counts);
}

// ---------------- Kernel 3: exclusive scan over NB buckets (1 block, 2/thread) ----------------
__global__ __launch_bounds__(1024) void bucket_scan(const int* __restrict__ counts,
                                                    int* __restrict__ base,
                                                    int* __restrict__ cursor) {
    __shared__ int sdata[1024];
    int t = threadIdx.x;
    int i0 = 2 * t, i1 = 2 * t + 1;
    int v0 = (i0 < NB) ? counts[i0] : 0;
    int v1 = (i1 < NB) ? counts[i1] : 0;
    int s = v0 + v1;
    sdata[t] = s;
    __syncthreads();
    for (int d = 1; d < 1024; d <<= 1) {
        int x = (t >= d) ? sdata[t - d] : 0;
        __syncthreads();
        sdata[t] += x;
        __syncthreads();
    }
    int excl = sdata[t] - s;
    if (i0 < NB) { base[i0] = excl;      cursor[i0] = excl; }
    if (i1 < NB) { base[i1] = excl + v0; cursor[i1] = excl + v0; }
}

// ---------------- Kernel 4: LDS-staged binning (coalesced scatter) ----------------
__global__ __launch_bounds__(512) void bin_edges(const int* __restrict__ src,
                                                 const int* __restrict__ dst,
                                                 const float* __restrict__ ew,
                                                 int* __restrict__ cursor,
                                                 int2* __restrict__ epack) {
    __shared__ int   hist[NB];
    __shared__ int   loff[NB];
    __shared__ int   gbase[NB];
    __shared__ int   ssum[512];
    __shared__ int2  buf[ETILE];      // 64 KB
    __shared__ short bkt[ETILE];      // 16 KB

    int tid = threadIdx.x;
    int tileStart = blockIdx.x * ETILE;
    int tileN = N_EDGES - tileStart; if (tileN > ETILE) tileN = ETILE;

    for (int i = tid; i < NB; i += 512) hist[i] = 0;
    __syncthreads();

    // pass A: ranks via LDS histogram (cache dst in registers)
    int rank[ETILE / 512];
    int dreg[ETILE / 512];
    #pragma unroll
    for (int k = 0; k < ETILE / 512; ++k) {
        int e = tileStart + k * 512 + tid;
        dreg[k] = (e < N_EDGES) ? dst[e] : 0;
        rank[k] = (e < N_EDGES) ? atomicAdd(&hist[dreg[k] >> BSHIFT], 1) : 0;
    }
    __syncthreads();

    // reserve global space per bucket
    for (int i = tid; i < NB; i += 512) {
        int c = hist[i];
        gbase[i] = c ? atomicAdd(&cursor[i], c) : 0;
    }

    // exclusive scan of hist -> loff (4 entries per thread, NB=1563 <= 2048)
    int a[4], lsum = 0;
    #pragma unroll
    for (int c = 0; c < 4; ++c) {
        int idx = 4 * tid + c;
        a[c] = (idx < NB) ? hist[idx] : 0;
        lsum += a[c];
    }
    ssum[tid] = lsum;
    __syncthreads();
    for (int d = 1; d < 512; d <<= 1) {
        int x = (tid >= d) ? ssum[tid - d] : 0;
        __syncthreads();
        ssum[tid] += x;
        __syncthreads();
    }
    int excl = ssum[tid] - lsum;
    #pragma unroll
    for (int c = 0; c < 4; ++c) {
        int idx = 4 * tid + c;
        if (idx < NB) { loff[idx] = excl; excl += a[c]; }
    }
    __syncthreads();

    // pass B: stage edges into LDS in bucket order
    #pragma unroll
    for (int k = 0; k < ETILE / 512; ++k) {
        int e = tileStart + k * 512 + tid;
        if (e < N_EDGES) {
            int d = dreg[k];
            int b = d >> BSHIFT;
            int slot = loff[b] + rank[k];
            int2 p;
            p.x = (src[e] & 0xFFFF) | (d << 16);   // src 16b | full dst 16b
            p.y = __float_as_int(ew[e]);
            buf[slot] = p;
            bkt[slot] = (short)b;
        }
    }
    __syncthreads();

    // streaming writeout: consecutive slots -> consecutive global positions
    for (int idx = tid; idx < tileN; idx += 512) {
        int b = bkt[idx];
        epack[gbase[b] + idx - loff[b]] = buf[idx];
    }
}

// ---------------- Kernel 6: per-bucket aggregate + bias + log-softmax ----------------
// One 512-thread block per 32-node bucket. Per-wave 128-edge chunks: metadata
// via 2 coalesced int2 loads + compile-time shfl broadcast; half-wave dword
// gathers (1 cache line per edge, 2 edges per instruction); 8-deep
// double-buffered named-register batches; per-edge ds_add into the bucket's
// LDS accumulator (no sort needed, no global atomics). Fused lsm epilogue.
#define LD1(X, jb, k) \
    px##X##k = __shfl((((jb) * 8 + (k)) < 32 ? E0.x : E1.x), ((2 * ((jb) * 8 + (k))) & 63) | h); \
    pw##X##k = __shfl((((jb) * 8 + (k)) < 32 ? E0.y : E1.y), ((2 * ((jb) * 8 + (k))) & 63) | h);
#define LR1(X, k) \
    R##X##k = *reinterpret_cast<const unsigned*>(xw + (size_t)(px##X##k & 0xFFFF) * XW_LD + (cp << 1));
#define LDB(X, jb) \
    LD1(X, jb, 0) LD1(X, jb, 1) LD1(X, jb, 2) LD1(X, jb, 3) \
    LD1(X, jb, 4) LD1(X, jb, 5) LD1(X, jb, 6) LD1(X, jb, 7) \
    LR1(X, 0) LR1(X, 1) LR1(X, 2) LR1(X, 3) LR1(X, 4) LR1(X, 5) LR1(X, 6) LR1(X, 7)
#define PR1(X, k) { \
    float wf = __int_as_float(pw##X##k); \
    if (act) { \
        int nd = (int)(((unsigned)px##X##k >> 16) & (BNODES - 1)); \
        atomicAdd(&acc[nd][cp << 1],       wf * bf2f(R##X##k & 0xFFFFu)); \
        atomicAdd(&acc[nd][(cp << 1) + 1], wf * bf2f(R##X##k >> 16)); \
    } }
#define PRB(X) PR1(X,0) PR1(X,1) PR1(X,2) PR1(X,3) PR1(X,4) PR1(X,5) PR1(X,6) PR1(X,7)

__global__ __launch_bounds__(512) void bucket_agg_lsm(
        const int* __restrict__ base, const int* __restrict__ cursor,
        const int2* __restrict__ epack, const unsigned short* __restrict__ xw,
        const float* __restrict__ bias, float* __restrict__ out) {
    __shared__ float acc[BNODES][OUT_CH];   // 6 KB

    int b   = blockIdx.x;
    int tid = threadIdx.x, lane = tid & 63, wid = tid >> 6;   // 8 waves

    for (int i = tid; i < BNODES * OUT_CH; i += 512)
        reinterpret_cast<float*>(acc)[i] = 0.f;
    __syncthreads();

    int lo = base[b], hi = cursor[b];
    int len = hi - lo;

    int h  = lane >> 5;                   // half: even / odd edges in chunk
    int cp = lane & 31;                   // channel pair (cp<24 real)
    bool act = (cp < 24);

    int pxA0, pxA1, pxA2, pxA3, pxA4, pxA5, pxA6, pxA7;
    int pwA0, pwA1, pwA2, pwA3, pwA4, pwA5, pwA6, pwA7;
    int pxB0, pxB1, pxB2, pxB3, pxB4, pxB5, pxB6, pxB7;
    int pwB0, pwB1, pwB2, pwB3, pwB4, pwB5, pwB6, pwB7;
    unsigned RA0, RA1, RA2, RA3, RA4, RA5, RA6, RA7;
    unsigned RB0, RB1, RB2, RB3, RB4, RB5, RB6, RB7;

    // chunked main: wave wid takes chunks lo + (wid + 8k)*128
    for (int i = lo + wid * 128; i + 128 <= hi; i += 8 * 128) {
        int2 E0 = epack[i + lane];
        int2 E1 = epack[i + 64 + lane];
        LDB(A, 0)
        LDB(B, 1) PRB(A)
        LDB(A, 2) PRB(B)
        LDB(B, 3) PRB(A)
        LDB(A, 4) PRB(B)
        LDB(B, 5) PRB(A)
        LDB(A, 6) PRB(B)
        LDB(B, 7) PRB(A)
        PRB(B)
    }

    // tail (< 128 edges): spread across 16 half-waves, <=8 serial edges each
    {
        int tailStart = lo + (len & ~127);
        int hw = tid >> 5;                // half-wave id 0..15
        for (int j = tailStart + hw; j < hi; j += 16) {
            int2 M = epack[j];
            float wf = __int_as_float(M.y);
            unsigned R = *reinterpret_cast<const unsigned*>(
                xw + (size_t)(M.x & 0xFFFF) * XW_LD + (cp << 1));
            if (act) {
                int nd = (int)(((unsigned)M.x >> 16) & (BNODES - 1));
                atomicAdd(&acc[nd][cp << 1],       wf * bf2f(R & 0xFFFFu));
                atomicAdd(&acc[nd][(cp << 1) + 1], wf * bf2f(R >> 16));
            }
        }
    }
    __syncthreads();

    // epilogue: bias + log-softmax per node (4 nodes per wave), plain stores
    bool ch = (lane < OUT_CH);
    float bv = ch ? bias[lane] : 0.f;
    int node0 = b << BSHIFT;
    for (int n = wid; n < BNODES; n += 8) {
        int node = node0 + n;
        if (node >= N_NODES) break;
        float v = ch ? (acc[n][lane] + bv) : -INFINITY;
        float m = v;
        #pragma unroll
        for (int d = 32; d >= 1; d >>= 1) m = fmaxf(m, __shfl_xor(m, d));
        float e = ch ? expf(v - m) : 0.f;
        float s = e;
        #pragma unroll
        for (int d = 32; d >= 1; d >>= 1) s += __shfl_xor(s, d);
        float lse = m + logf(s);
        if (ch) out[(size_t)node * OUT_CH + lane] = v - lse;
    }
}

extern "C" void kernel_launch(void* const* d_in, const int* in_sizes, int n_in,
                              void* d_out, int out_size, void* d_ws, size_t ws_size,
                              hipStream_t stream) {
    const int*   edge_index = (const int*)d_in[0];
    const float* features   = (const float*)d_in[1];
    const float* eweights   = (const float*)d_in[2];
    const float* weight     = (const float*)d_in[3];
    const float* bias       = (const float*)d_in[4];

    const int* src = edge_index;            // edge_index[0, :]
    const int* dst = edge_index + N_EDGES;  // edge_index[1, :]

    float* out = (float*)d_out;

    // Workspace layout (bytes):
    //   xw (bf16, LD=64) @ 0 : 50000*64*2 = 6,400,000
    //   counts  @ 9,600,000 : NB*4 (~6.3 KB)
    //   base    @ 9,616,000 : NB*4
    //   cursor  @ 9,632,000 : NB*4
    //   epack   @ 9,648,000 : 12,800,000   (ends 22,448,000)
    //   wfrag   @ 22,448,000 : 49,152
    char* ws = (char*)d_ws;
    unsigned short* xw    = (unsigned short*)(ws + 0);
    int*   counts = (int*)  (ws + 9600000);
    int*   base   = (int*)  (ws + 9616000);
    int*   cursor = (int*)  (ws + 9632000);
    int2*  epack  = (int2*) (ws + 9648000);
    unsigned short* wfrag = (unsigned short*)(ws + 22448000);

    hipMemsetAsync(counts, 0, NB * sizeof(int), stream);

    // 0) pre-format B fragments (once per launch)
    prep_bfrag<<<(IN_CH * OUT_CH / 4 + 255) / 256, 256, 0, stream>>>(weight, wfrag);

    // 1) gemm (bf16 MFMA) and dst-histogram, concurrent in one launch
    gemm_hist<<<GEMM_BLOCKS + HIST_BLOCKS, 256, 0, stream>>>(features, wfrag, xw,
                                                             dst, counts);

    // 2) scan + bucket binning (coarse, write-coalesced); no in-bucket sort needed
    bucket_scan<<<1, 1024, 0, stream>>>(counts, base, cursor);
    bin_edges<<<(N_EDGES + ETILE - 1) / ETILE, 512, 0, stream>>>(src, dst, eweights,
                                                                 cursor, epack);

    // 3) per-bucket aggregate (ds_add per edge) + bias + log-softmax
    bucket_agg_lsm<<<NB, 512, 0, stream>>>(base, cursor, epack, xw, bias, out);
}

// Round 17
// 531.010 us; speedup vs baseline: 1.0058x; 1.0058x over previous
//
#include <hip/hip_runtime.h>
#include <math.h>

#define N_NODES 50000
#define N_EDGES 1600000
#define IN_CH   512
#define OUT_CH  48
#define XW_LD   64                   // xw row stride in ushorts -> 128B, one cache line
#define N_TILES (N_NODES / 16)       // 3125 row-tiles, exact

#define BSHIFT  5                    // 32 nodes per bucket
#define BNODES  32
#define NB      ((N_NODES + BNODES - 1) / BNODES)   // 1563 buckets
#define ETILE   8192                 // edges per bin_edges block

#define BFRAG_SHORTS (16 * 3 * 64 * 8)   // 24576 shorts = 48 KB fragment image of B
#define GEMM_BLOCKS ((N_TILES + 3) / 4)  // 782
#define HIST_BLOCKS 256

typedef __attribute__((ext_vector_type(8))) short bf16x8;
typedef __attribute__((ext_vector_type(4))) float f32x4;

// fp32 -> bf16 (round-to-nearest-even), branch-free
static __device__ inline short f2bf(float x) {
    union { float f; unsigned u; } in; in.f = x;
    unsigned r = in.u + 0x7fffu + ((in.u >> 16) & 1u);
    return (short)(r >> 16);
}
static __device__ inline float bf2f(unsigned v16) {
    union { unsigned u; float f; } o; o.u = v16 << 16; return o.f;
}

// ---------------- Kernel 0: pre-format B into MFMA fragment layout (once) ----------------
__global__ __launch_bounds__(256) void prep_bfrag(const float* __restrict__ w,
                                                  unsigned short* __restrict__ wfrag) {
    int i = blockIdx.x * blockDim.x + threadIdx.x;       // one float4 per thread
    if (i >= IN_CH * OUT_CH / 4) return;
    int flat = i * 4;
    int k   = flat / OUT_CH;
    int col = flat % OUT_CH;
    float4 v = *reinterpret_cast<const float4*>(w + flat);
    int s = k >> 5, j = k & 7, q = (k >> 3) & 3;
    float vv[4] = {v.x, v.y, v.z, v.w};
    #pragma unroll
    for (int c = 0; c < 4; ++c) {
        int cc = col + c;
        int t  = cc >> 4;
        int ln = (cc & 15) | (q << 4);
        wfrag[((s * 3 + t) * 64 + ln) * 8 + j] = (unsigned short)f2bf(vv[c]);
    }
}

// ---------------- Kernel 1 (merged): gemm blocks + hist blocks ----------------
static __device__ void gemm_body(char* smem, const float* __restrict__ f,
                                 const unsigned short* __restrict__ wfrag,
                                 unsigned short* __restrict__ xw) {
    short* sBl = reinterpret_cast<short*>(smem);

    int tid  = threadIdx.x;
    int lane = tid & 63;
    int wid  = tid >> 6;

    {
        const uint4* gw = reinterpret_cast<const uint4*>(wfrag);
        uint4*       sw = reinterpret_cast<uint4*>(smem);
        #pragma unroll
        for (int i = 0; i < BFRAG_SHORTS / 8 / 256; ++i)   // 12 iterations
            sw[i * 256 + tid] = gw[i * 256 + tid];
    }
    __syncthreads();

    int tile = blockIdx.x * 4 + wid;
    if (tile >= N_TILES) return;

    const bf16x8* sB = reinterpret_cast<const bf16x8*>(sBl);

    int row = tile * 16 + (lane & 15);
    const float* fp = f + (size_t)row * IN_CH + ((lane >> 4) << 3);

    f32x4 acc0 = {0.f, 0.f, 0.f, 0.f};
    f32x4 acc1 = {0.f, 0.f, 0.f, 0.f};
    f32x4 acc2 = {0.f, 0.f, 0.f, 0.f};

    float4 a0[2], a1[2];
    a0[0] = *reinterpret_cast<const float4*>(fp);
    a1[0] = *reinterpret_cast<const float4*>(fp + 4);

    #pragma unroll
    for (int s = 0; s < 16; ++s) {
        const int cb = s & 1, nb = cb ^ 1;
        if (s + 1 < 16) {                                  // prefetch next K-step
            a0[nb] = *reinterpret_cast<const float4*>(fp + (s + 1) * 32);
            a1[nb] = *reinterpret_cast<const float4*>(fp + (s + 1) * 32 + 4);
        }
        bf16x8 a;
        a[0] = f2bf(a0[cb].x); a[1] = f2bf(a0[cb].y);
        a[2] = f2bf(a0[cb].z); a[3] = f2bf(a0[cb].w);
        a[4] = f2bf(a1[cb].x); a[5] = f2bf(a1[cb].y);
        a[6] = f2bf(a1[cb].z); a[7] = f2bf(a1[cb].w);
        bf16x8 b0 = sB[(s * 3 + 0) * 64 + lane];
        bf16x8 b1 = sB[(s * 3 + 1) * 64 + lane];
        bf16x8 b2 = sB[(s * 3 + 2) * 64 + lane];
        acc0 = __builtin_amdgcn_mfma_f32_16x16x32_bf16(a, b0, acc0, 0, 0, 0);
        acc1 = __builtin_amdgcn_mfma_f32_16x16x32_bf16(a, b1, acc1, 0, 0, 0);
        acc2 = __builtin_amdgcn_mfma_f32_16x16x32_bf16(a, b2, acc2, 0, 0, 0);
    }

    unsigned short* orow = xw + (size_t)tile * 16 * XW_LD;
    int c  = lane & 15;
    int r0 = (lane >> 4) * 4;
    #pragma unroll
    for (int r = 0; r < 4; ++r) {
        orow[(size_t)(r0 + r) * XW_LD +  0 + c] = (unsigned short)f2bf(acc0[r]);
        orow[(size_t)(r0 + r) * XW_LD + 16 + c] = (unsigned short)f2bf(acc1[r]);
        orow[(size_t)(r0 + r) * XW_LD + 32 + c] = (unsigned short)f2bf(acc2[r]);
    }
}

static __device__ void hist_body(char* smem, int bid, const int* __restrict__ dst,
                                 int* __restrict__ counts) {
    int* hc = reinterpret_cast<int*>(smem);
    for (int i = threadIdx.x; i < NB; i += 256) hc[i] = 0;
    __syncthreads();
    for (int e = bid * 256 + threadIdx.x; e < N_EDGES; e += HIST_BLOCKS * 256)
        atomicAdd(&hc[dst[e] >> BSHIFT], 1);
    __syncthreads();
    for (int i = threadIdx.x; i < NB; i += 256)
        if (hc[i]) atomicAdd(&counts[i], hc[i]);
}

__global__ __launch_bounds__(256) void gemm_hist(const float* __restrict__ f,
                                                 const unsigned short* __restrict__ wfrag,
                                                 unsigned short* __restrict__ xw,
                                                 const int* __restrict__ dst,
                                                 int* __restrict__ counts) {
    __shared__ __align__(16) char smem[BFRAG_SHORTS * 2];   // 48 KB union
    if (blockIdx.x < GEMM_BLOCKS) gemm_body(smem, f, wfrag, xw);
    else                          hist_body(smem, blockIdx.x - GEMM_BLOCKS, dst, counts);
}

// ---------------- Kernel 3: exclusive scan over NB buckets (1 block, 2/thread) ----------------
__global__ __launch_bounds__(1024) void bucket_scan(const int* __restrict__ counts,
                                                    int* __restrict__ base,
                                                    int* __restrict__ cursor) {
    __shared__ int sdata[1024];
    int t = threadIdx.x;
    int i0 = 2 * t, i1 = 2 * t + 1;
    int v0 = (i0 < NB) ? counts[i0] : 0;
    int v1 = (i1 < NB) ? counts[i1] : 0;
    int s = v0 + v1;
    sdata[t] = s;
    __syncthreads();
    for (int d = 1; d < 1024; d <<= 1) {
        int x = (t >= d) ? sdata[t - d] : 0;
        __syncthreads();
        sdata[t] += x;
        __syncthreads();
    }
    int excl = sdata[t] - s;
    if (i0 < NB) { base[i0] = excl;      cursor[i0] = excl; }
    if (i1 < NB) { base[i1] = excl + v0; cursor[i1] = excl + v0; }
}

// ---------------- Kernel 4: LDS-staged binning (coalesced scatter) ----------------
__global__ __launch_bounds__(512) void bin_edges(const int* __restrict__ src,
                                                 const int* __restrict__ dst,
                                                 const float* __restrict__ ew,
                                                 int* __restrict__ cursor,
                                                 int2* __restrict__ epack) {
    __shared__ int   hist[NB];
    __shared__ int   loff[NB];
    __shared__ int   gbase[NB];
    __shared__ int   ssum[512];
    __shared__ int2  buf[ETILE];      // 64 KB
    __shared__ short bkt[ETILE];      // 16 KB

    int tid = threadIdx.x;
    int tileStart = blockIdx.x * ETILE;
    int tileN = N_EDGES - tileStart; if (tileN > ETILE) tileN = ETILE;

    for (int i = tid; i < NB; i += 512) hist[i] = 0;
    __syncthreads();

    // pass A: ranks via LDS histogram (cache dst in registers)
    int rank[ETILE / 512];
    int dreg[ETILE / 512];
    #pragma unroll
    for (int k = 0; k < ETILE / 512; ++k) {
        int e = tileStart + k * 512 + tid;
        dreg[k] = (e < N_EDGES) ? dst[e] : 0;
        rank[k] = (e < N_EDGES) ? atomicAdd(&hist[dreg[k] >> BSHIFT], 1) : 0;
    }
    __syncthreads();

    // reserve global space per bucket
    for (int i = tid; i < NB; i += 512) {
        int c = hist[i];
        gbase[i] = c ? atomicAdd(&cursor[i], c) : 0;
    }

    // exclusive scan of hist -> loff (4 entries per thread, NB=1563 <= 2048)
    int a[4], lsum = 0;
    #pragma unroll
    for (int c = 0; c < 4; ++c) {
        int idx = 4 * tid + c;
        a[c] = (idx < NB) ? hist[idx] : 0;
        lsum += a[c];
    }
    ssum[tid] = lsum;
    __syncthreads();
    for (int d = 1; d < 512; d <<= 1) {
        int x = (tid >= d) ? ssum[tid - d] : 0;
        __syncthreads();
        ssum[tid] += x;
        __syncthreads();
    }
    int excl = ssum[tid] - lsum;
    #pragma unroll
    for (int c = 0; c < 4; ++c) {
        int idx = 4 * tid + c;
        if (idx < NB) { loff[idx] = excl; excl += a[c]; }
    }
    __syncthreads();

    // pass B: stage edges into LDS in bucket order
    #pragma unroll
    for (int k = 0; k < ETILE / 512; ++k) {
        int e = tileStart + k * 512 + tid;
        if (e < N_EDGES) {
            int d = dreg[k];
            int b = d >> BSHIFT;
            int slot = loff[b] + rank[k];
            int2 p;
            p.x = (src[e] & 0xFFFF) | (d << 16);   // src 16b | full dst 16b
            p.y = __float_as_int(ew[e]);
            buf[slot] = p;
            bkt[slot] = (short)b;
        }
    }
    __syncthreads();

    // streaming writeout: consecutive slots -> consecutive global positions
    for (int idx = tid; idx < tileN; idx += 512) {
        int b = bkt[idx];
        epack[gbase[b] + idx - loff[b]] = buf[idx];
    }
}

// ---------------- Kernel 6: per-bucket aggregate + bias + log-softmax ----------------
// One 512-thread block per 32-node bucket. Per-wave 128-edge chunks: metadata
// via 2 coalesced int2 loads + compile-time shfl broadcast; half-wave dword
// gathers (1 cache line per edge, 2 edges per instruction); 8-deep
// double-buffered named-register batches; per-edge ds_add into the bucket's
// LDS accumulator (no sort needed, no global atomics). Fused lsm epilogue.
#define LD1(X, jb, k) \
    px##X##k = __shfl((((jb) * 8 + (k)) < 32 ? E0.x : E1.x), ((2 * ((jb) * 8 + (k))) & 63) | h); \
    pw##X##k = __shfl((((jb) * 8 + (k)) < 32 ? E0.y : E1.y), ((2 * ((jb) * 8 + (k))) & 63) | h);
#define LR1(X, k) \
    R##X##k = *reinterpret_cast<const unsigned*>(xw + (size_t)(px##X##k & 0xFFFF) * XW_LD + (cp << 1));
#define LDB(X, jb) \
    LD1(X, jb, 0) LD1(X, jb, 1) LD1(X, jb, 2) LD1(X, jb, 3) \
    LD1(X, jb, 4) LD1(X, jb, 5) LD1(X, jb, 6) LD1(X, jb, 7) \
    LR1(X, 0) LR1(X, 1) LR1(X, 2) LR1(X, 3) LR1(X, 4) LR1(X, 5) LR1(X, 6) LR1(X, 7)
#define PR1(X, k) { \
    float wf = __int_as_float(pw##X##k); \
    if (act) { \
        int nd = (int)(((unsigned)px##X##k >> 16) & (BNODES - 1)); \
        atomicAdd(&acc[nd][cp << 1],       wf * bf2f(R##X##k & 0xFFFFu)); \
        atomicAdd(&acc[nd][(cp << 1) + 1], wf * bf2f(R##X##k >> 16)); \
    } }
#define PRB(X) PR1(X,0) PR1(X,1) PR1(X,2) PR1(X,3) PR1(X,4) PR1(X,5) PR1(X,6) PR1(X,7)

__global__ __launch_bounds__(512) void bucket_agg_lsm(
        const int* __restrict__ base, const int* __restrict__ cursor,
        const int2* __restrict__ epack, const unsigned short* __restrict__ xw,
        const float* __restrict__ bias, float* __restrict__ out) {
    __shared__ float acc[BNODES][OUT_CH];   // 6 KB

    int b   = blockIdx.x;
    int tid = threadIdx.x, lane = tid & 63, wid = tid >> 6;   // 8 waves

    for (int i = tid; i < BNODES * OUT_CH; i += 512)
        reinterpret_cast<float*>(acc)[i] = 0.f;
    __syncthreads();

    int lo = base[b], hi = cursor[b];
    int len = hi - lo;

    int h  = lane >> 5;                   // half: even / odd edges in chunk
    int cp = lane & 31;                   // channel pair (cp<24 real)
    bool act = (cp < 24);

    int pxA0, pxA1, pxA2, pxA3, pxA4, pxA5, pxA6, pxA7;
    int pwA0, pwA1, pwA2, pwA3, pwA4, pwA5, pwA6, pwA7;
    int pxB0, pxB1, pxB2, pxB3, pxB4, pxB5, pxB6, pxB7;
    int pwB0, pwB1, pwB2, pwB3, pwB4, pwB5, pwB6, pwB7;
    unsigned RA0, RA1, RA2, RA3, RA4, RA5, RA6, RA7;
    unsigned RB0, RB1, RB2, RB3, RB4, RB5, RB6, RB7;

    // chunked main: wave wid takes chunks lo + (wid + 8k)*128
    for (int i = lo + wid * 128; i + 128 <= hi; i += 8 * 128) {
        int2 E0 = epack[i + lane];
        int2 E1 = epack[i + 64 + lane];
        LDB(A, 0)
        LDB(B, 1) PRB(A)
        LDB(A, 2) PRB(B)
        LDB(B, 3) PRB(A)
        LDB(A, 4) PRB(B)
        LDB(B, 5) PRB(A)
        LDB(A, 6) PRB(B)
        LDB(B, 7) PRB(A)
        PRB(B)
    }

    // tail (< 128 edges): spread across 16 half-waves, <=8 serial edges each
    {
        int tailStart = lo + (len & ~127);
        int hw = tid >> 5;                // half-wave id 0..15
        for (int j = tailStart + hw; j < hi; j += 16) {
            int2 M = epack[j];
            float wf = __int_as_float(M.y);
            unsigned R = *reinterpret_cast<const unsigned*>(
                xw + (size_t)(M.x & 0xFFFF) * XW_LD + (cp << 1));
            if (act) {
                int nd = (int)(((unsigned)M.x >> 16) & (BNODES - 1));
                atomicAdd(&acc[nd][cp << 1],       wf * bf2f(R & 0xFFFFu));
                atomicAdd(&acc[nd][(cp << 1) + 1], wf * bf2f(R >> 16));
            }
        }
    }
    __syncthreads();

    // epilogue: bias + log-softmax per node (4 nodes per wave), plain stores
    bool ch = (lane < OUT_CH);
    float bv = ch ? bias[lane] : 0.f;
    int node0 = b << BSHIFT;
    for (int n = wid; n < BNODES; n += 8) {
        int node = node0 + n;
        if (node >= N_NODES) break;
        float v = ch ? (acc[n][lane] + bv) : -INFINITY;
        float m = v;
        #pragma unroll
        for (int d = 32; d >= 1; d >>= 1) m = fmaxf(m, __shfl_xor(m, d));
        float e = ch ? expf(v - m) : 0.f;
        float s = e;
        #pragma unroll
        for (int d = 32; d >= 1; d >>= 1) s += __shfl_xor(s, d);
        float lse = m + logf(s);
        if (ch) out[(size_t)node * OUT_CH + lane] = v - lse;
    }
}

extern "C" void kernel_launch(void* const* d_in, const int* in_sizes, int n_in,
                              void* d_out, int out_size, void* d_ws, size_t ws_size,
                              hipStream_t stream) {
    const int*   edge_index = (const int*)d_in[0];
    const float* features   = (const float*)d_in[1];
    const float* eweights   = (const float*)d_in[2];
    const float* weight     = (const float*)d_in[3];
    const float* bias       = (const float*)d_in[4];

    const int* src = edge_index;            // edge_index[0, :]
    const int* dst = edge_index + N_EDGES;  // edge_index[1, :]

    float* out = (float*)d_out;

    // Workspace layout (bytes):
    //   xw (bf16, LD=64) @ 0 : 50000*64*2 = 6,400,000
    //   counts  @ 9,600,000 : NB*4 (~6.3 KB)
    //   base    @ 9,616,000 : NB*4
    //   cursor  @ 9,632,000 : NB*4
    //   epack   @ 9,648,000 : 12,800,000   (ends 22,448,000)
    //   wfrag   @ 22,448,000 : 49,152
    char* ws = (char*)d_ws;
    unsigned short* xw    = (unsigned short*)(ws + 0);
    int*   counts = (int*)  (ws + 9600000);
    int*   base   = (int*)  (ws + 9616000);
    int*   cursor = (int*)  (ws + 9632000);
    int2*  epack  = (int2*) (ws + 9648000);
    unsigned short* wfrag = (unsigned short*)(ws + 22448000);

    hipMemsetAsync(counts, 0, NB * sizeof(int), stream);

    // 0) pre-format B fragments (once per launch)
    prep_bfrag<<<(IN_CH * OUT_CH / 4 + 255) / 256, 256, 0, stream>>>(weight, wfrag);

    // 1) gemm (bf16 MFMA) and dst-histogram, concurrent in one launch
    gemm_hist<<<GEMM_BLOCKS + HIST_BLOCKS, 256, 0, stream>>>(features, wfrag, xw,
                                                             dst, counts);

    // 2) scan + bucket binning (coarse, write-coalesced); no in-bucket sort needed
    bucket_scan<<<1, 1024, 0, stream>>>(counts, base, cursor);
    bin_edges<<<(N_EDGES + ETILE - 1) / ETILE, 512, 0, stream>>>(src, dst, eweights,
                                                                 cursor, epack);

    // 3) per-bucket aggregate (ds_add per edge) + bias + log-softmax
    bucket_agg_lsm<<<NB, 512, 0, stream>>>(base, cursor, epack, xw, bias, out);
}

// Round 18
// 181.095 us; speedup vs baseline: 2.9491x; 2.9322x over previous
//
#include <hip/hip_runtime.h>
#include <math.h>

#define N_NODES 50000
#define N_EDGES 1600000
#define IN_CH   512
#define OUT_CH  48
#define XW_LD   64                   // xw row stride in ushorts -> 128B, one cache line
#define N_TILES (N_NODES / 16)       // 3125 row-tiles, exact

#define BSHIFT  6                    // 64 nodes per bucket
#define BNODES  64
#define NB      ((N_NODES + BNODES - 1) / BNODES)   // 782 buckets
#define ETILE   8192                 // edges per bin_edges block
#define CAP     2816                 // max edges per bucket handled by sort (mean 2046)

#define BFRAG_SHORTS (16 * 3 * 64 * 8)   // 24576 shorts = 48 KB fragment image of B
#define GEMM_BLOCKS ((N_TILES + 3) / 4)  // 782
#define HIST_BLOCKS 256

typedef __attribute__((ext_vector_type(8))) short bf16x8;
typedef __attribute__((ext_vector_type(4))) float f32x4;

// fp32 -> bf16 (round-to-nearest-even), branch-free
static __device__ inline short f2bf(float x) {
    union { float f; unsigned u; } in; in.f = x;
    unsigned r = in.u + 0x7fffu + ((in.u >> 16) & 1u);
    return (short)(r >> 16);
}
static __device__ inline float bf2f(unsigned v16) {
    union { unsigned u; float f; } o; o.u = v16 << 16; return o.f;
}

// ---------------- Kernel 0: pre-format B into MFMA fragment layout (once) ----------------
__global__ __launch_bounds__(256) void prep_bfrag(const float* __restrict__ w,
                                                  unsigned short* __restrict__ wfrag) {
    int i = blockIdx.x * blockDim.x + threadIdx.x;       // one float4 per thread
    if (i >= IN_CH * OUT_CH / 4) return;
    int flat = i * 4;
    int k   = flat / OUT_CH;
    int col = flat % OUT_CH;
    float4 v = *reinterpret_cast<const float4*>(w + flat);
    int s = k >> 5, j = k & 7, q = (k >> 3) & 3;
    float vv[4] = {v.x, v.y, v.z, v.w};
    #pragma unroll
    for (int c = 0; c < 4; ++c) {
        int cc = col + c;
        int t  = cc >> 4;
        int ln = (cc & 15) | (q << 4);
        wfrag[((s * 3 + t) * 64 + ln) * 8 + j] = (unsigned short)f2bf(vv[c]);
    }
}

// ---------------- Kernel 1 (merged): gemm blocks + hist blocks ----------------
static __device__ void gemm_body(char* smem, const float* __restrict__ f,
                                 const unsigned short* __restrict__ wfrag,
                                 unsigned short* __restrict__ xw) {
    short* sBl = reinterpret_cast<short*>(smem);

    int tid  = threadIdx.x;
    int lane = tid & 63;
    int wid  = tid >> 6;

    {
        const uint4* gw = reinterpret_cast<const uint4*>(wfrag);
        uint4*       sw = reinterpret_cast<uint4*>(smem);
        #pragma unroll
        for (int i = 0; i < BFRAG_SHORTS / 8 / 256; ++i)   // 12 iterations
            sw[i * 256 + tid] = gw[i * 256 + tid];
    }
    __syncthreads();

    int tile = blockIdx.x * 4 + wid;
    if (tile >= N_TILES) return;

    const bf16x8* sB = reinterpret_cast<const bf16x8*>(sBl);

    int row = tile * 16 + (lane & 15);
    const float* fp = f + (size_t)row * IN_CH + ((lane >> 4) << 3);

    f32x4 acc0 = {0.f, 0.f, 0.f, 0.f};
    f32x4 acc1 = {0.f, 0.f, 0.f, 0.f};
    f32x4 acc2 = {0.f, 0.f, 0.f, 0.f};

    float4 a0[2], a1[2];
    a0[0] = *reinterpret_cast<const float4*>(fp);
    a1[0] = *reinterpret_cast<const float4*>(fp + 4);

    #pragma unroll
    for (int s = 0; s < 16; ++s) {
        const int cb = s & 1, nb = cb ^ 1;
        if (s + 1 < 16) {                                  // prefetch next K-step
            a0[nb] = *reinterpret_cast<const float4*>(fp + (s + 1) * 32);
            a1[nb] = *reinterpret_cast<const float4*>(fp + (s + 1) * 32 + 4);
        }
        bf16x8 a;
        a[0] = f2bf(a0[cb].x); a[1] = f2bf(a0[cb].y);
        a[2] = f2bf(a0[cb].z); a[3] = f2bf(a0[cb].w);
        a[4] = f2bf(a1[cb].x); a[5] = f2bf(a1[cb].y);
        a[6] = f2bf(a1[cb].z); a[7] = f2bf(a1[cb].w);
        bf16x8 b0 = sB[(s * 3 + 0) * 64 + lane];
        bf16x8 b1 = sB[(s * 3 + 1) * 64 + lane];
        bf16x8 b2 = sB[(s * 3 + 2) * 64 + lane];
        acc0 = __builtin_amdgcn_mfma_f32_16x16x32_bf16(a, b0, acc0, 0, 0, 0);
        acc1 = __builtin_amdgcn_mfma_f32_16x16x32_bf16(a, b1, acc1, 0, 0, 0);
        acc2 = __builtin_amdgcn_mfma_f32_16x16x32_bf16(a, b2, acc2, 0, 0, 0);
    }

    unsigned short* orow = xw + (size_t)tile * 16 * XW_LD;
    int c  = lane & 15;
    int r0 = (lane >> 4) * 4;
    #pragma unroll
    for (int r = 0; r < 4; ++r) {
        orow[(size_t)(r0 + r) * XW_LD +  0 + c] = (unsigned short)f2bf(acc0[r]);
        orow[(size_t)(r0 + r) * XW_LD + 16 + c] = (unsigned short)f2bf(acc1[r]);
        orow[(size_t)(r0 + r) * XW_LD + 32 + c] = (unsigned short)f2bf(acc2[r]);
    }
}

static __device__ void hist_body(char* smem, int bid, const int* __restrict__ dst,
                                 int* __restrict__ counts) {
    int* hc = reinterpret_cast<int*>(smem);
    for (int i = threadIdx.x; i < NB; i += 256) hc[i] = 0;
    __syncthreads();
    for (int e = bid * 256 + threadIdx.x; e < N_EDGES; e += HIST_BLOCKS * 256)
        atomicAdd(&hc[dst[e] >> BSHIFT], 1);
    __syncthreads();
    for (int i = threadIdx.x; i < NB; i += 256)
        if (hc[i]) atomicAdd(&counts[i], hc[i]);
}

__global__ __launch_bounds__(256) void gemm_hist(const float* __restrict__ f,
                                                 const unsigned short* __restrict__ wfrag,
                                                 unsigned short* __restrict__ xw,
                                                 const int* __restrict__ dst,
                                                 int* __restrict__ counts) {
    __shared__ __align__(16) char smem[BFRAG_SHORTS * 2];   // 48 KB union
    if (blockIdx.x < GEMM_BLOCKS) gemm_body(smem, f, wfrag, xw);
    else                          hist_body(smem, blockIdx.x - GEMM_BLOCKS, dst, counts);
}

// ---------------- Kernel 3: exclusive scan over NB buckets (1 block, 2/thread) ----------------
__global__ __launch_bounds__(1024) void bucket_scan(const int* __restrict__ counts,
                                                    int* __restrict__ base,
                                                    int* __restrict__ cursor) {
    __shared__ int sdata[1024];
    int t = threadIdx.x;
    int i0 = 2 * t, i1 = 2 * t + 1;
    int v0 = (i0 < NB) ? counts[i0] : 0;
    int v1 = (i1 < NB) ? counts[i1] : 0;
    int s = v0 + v1;
    sdata[t] = s;
    __syncthreads();
    for (int d = 1; d < 1024; d <<= 1) {
        int x = (t >= d) ? sdata[t - d] : 0;
        __syncthreads();
        sdata[t] += x;
        __syncthreads();
    }
    int excl = sdata[t] - s;
    if (i0 < NB) { base[i0] = excl;      cursor[i0] = excl; }
    if (i1 < NB) { base[i1] = excl + v0; cursor[i1] = excl + v0; }
}

// ---------------- Kernel 4: LDS-staged binning (coalesced scatter) ----------------
__global__ __launch_bounds__(512) void bin_edges(const int* __restrict__ src,
                                                 const int* __restrict__ dst,
                                                 const float* __restrict__ ew,
                                                 int* __restrict__ cursor,
                                                 int2* __restrict__ epack) {
    __shared__ int   hist[NB];
    __shared__ int   loff[NB];
    __shared__ int   gbase[NB];
    __shared__ int   ssum[512];
    __shared__ int2  buf[ETILE];      // 64 KB
    __shared__ short bkt[ETILE];      // 16 KB

    int tid = threadIdx.x;
    int tileStart = blockIdx.x * ETILE;
    int tileN = N_EDGES - tileStart; if (tileN > ETILE) tileN = ETILE;

    for (int i = tid; i < NB; i += 512) hist[i] = 0;
    __syncthreads();

    // pass A: ranks via LDS histogram (cache dst in registers)
    int rank[ETILE / 512];
    int dreg[ETILE / 512];
    #pragma unroll
    for (int k = 0; k < ETILE / 512; ++k) {
        int e = tileStart + k * 512 + tid;
        dreg[k] = (e < N_EDGES) ? dst[e] : 0;
        rank[k] = (e < N_EDGES) ? atomicAdd(&hist[dreg[k] >> BSHIFT], 1) : 0;
    }
    __syncthreads();

    // reserve global space per bucket
    for (int i = tid; i < NB; i += 512) {
        int c = hist[i];
        gbase[i] = c ? atomicAdd(&cursor[i], c) : 0;
    }

    // exclusive scan of hist -> loff (4 entries per thread)
    int a[4], lsum = 0;
    #pragma unroll
    for (int c = 0; c < 4; ++c) {
        int idx = 4 * tid + c;
        a[c] = (idx < NB) ? hist[idx] : 0;
        lsum += a[c];
    }
    ssum[tid] = lsum;
    __syncthreads();
    for (int d = 1; d < 512; d <<= 1) {
        int x = (tid >= d) ? ssum[tid - d] : 0;
        __syncthreads();
        ssum[tid] += x;
        __syncthreads();
    }
    int excl = ssum[tid] - lsum;
    #pragma unroll
    for (int c = 0; c < 4; ++c) {
        int idx = 4 * tid + c;
        if (idx < NB) { loff[idx] = excl; excl += a[c]; }
    }
    __syncthreads();

    // pass B: stage edges into LDS in bucket order
    #pragma unroll
    for (int k = 0; k < ETILE / 512; ++k) {
        int e = tileStart + k * 512 + tid;
        if (e < N_EDGES) {
            int d = dreg[k];
            int b = d >> BSHIFT;
            int slot = loff[b] + rank[k];
            int2 p;
            p.x = (src[e] & 0xFFFF) | (d << 16);   // src 16b | full dst 16b
            p.y = __float_as_int(ew[e]);
            buf[slot] = p;
            bkt[slot] = (short)b;
        }
    }
    __syncthreads();

    // streaming writeout: consecutive slots -> consecutive global positions
    for (int idx = tid; idx < tileN; idx += 512) {
        int b = bkt[idx];
        epack[gbase[b] + idx - loff[b]] = buf[idx];
    }
}

// ---------------- Kernel 5: in-bucket sort by node ----------------
__global__ __launch_bounds__(256) void sort_bucket(const int* __restrict__ base,
                                                   const int* __restrict__ cursor,
                                                   int2* __restrict__ epack) {
    __shared__ int2  A[CAP];      // 22.5 KB
    __shared__ int2  B[CAP];      // 22.5 KB
    __shared__ short rk[CAP];     // 5.6 KB
    __shared__ int   hist[BNODES];
    __shared__ int   loff[BNODES];

    int b  = blockIdx.x;
    int lo = base[b], hi = cursor[b];
    int len = hi - lo;
    if (len <= 0 || len > CAP) return;   // oversize: leave unsorted (agg still correct)

    int tid = threadIdx.x;
    if (tid < BNODES) hist[tid] = 0;
    for (int i = tid; i < len; i += 256) A[i] = epack[lo + i];
    __syncthreads();

    for (int i = tid; i < len; i += 256) {
        int key = (((unsigned)A[i].x) >> 16) & (BNODES - 1);
        rk[i] = (short)atomicAdd(&hist[key], 1);
    }
    __syncthreads();

    if (tid < BNODES) {           // wave 0: exclusive scan of 64 counters
        int v = hist[tid];
        int s = v;
        #pragma unroll
        for (int d = 1; d < 64; d <<= 1) {
            int t = __shfl_up(s, d);
            if (tid >= d) s += t;
        }
        loff[tid] = s - v;
    }
    __syncthreads();

    for (int i = tid; i < len; i += 256) {
        int key = (((unsigned)A[i].x) >> 16) & (BNODES - 1);
        B[loff[key] + rk[i]] = A[i];
    }
    __syncthreads();

    for (int i = tid; i < len; i += 256) epack[lo + i] = B[i];
}

// ---------------- Kernel 6: per-bucket aggregate + bias + log-softmax ----------------
// One 512-thread block (8 waves) per 64-node bucket; 782 blocks all co-resident
// (4 blocks/CU, 32 waves/CU). Each wave owns a contiguous ~256-edge slice:
// r12's proven gather core (shfl-broadcast metadata, half-wave dword streams,
// 8-deep batches) with rare run-boundary flushes into the bucket's LDS tile.
// Fused bias + log-softmax epilogue, plain coalesced stores.
__global__ __launch_bounds__(512, 8) void bucket_agg_lsm(
        const int* __restrict__ base, const int* __restrict__ cursor,
        const int2* __restrict__ epack, const unsigned short* __restrict__ xw,
        const float* __restrict__ bias, float* __restrict__ out) {
    __shared__ float acc[BNODES][OUT_CH];   // 12 KB

    int b   = blockIdx.x;
    int tid = threadIdx.x, lane = tid & 63, wid = tid >> 6;   // 8 waves

    for (int i = tid; i < BNODES * OUT_CH; i += 512)
        reinterpret_cast<float*>(acc)[i] = 0.f;
    __syncthreads();

    int lo = base[b], hi = cursor[b];
    int len = hi - lo;
    int per = (len + 7) >> 3;
    int myLo = lo + wid * per;
    int myHi = myLo + per; if (myHi > hi) myHi = hi;

    int h  = lane >> 5;                   // half: even / odd edges
    int cp = lane & 31;                   // channel pair (cp<24 real)
    bool act = (cp < 24);

    float ax = 0.f, ay = 0.f;
    int cur = -1;

    int i = myLo;
    for (; i + 128 <= myHi; i += 128) {
        int2 E0 = epack[i + lane];
        int2 E1 = epack[i + 64 + lane];

        int px[2][8]; float pw[2][8]; unsigned u[2][8];

        #pragma unroll
        for (int k = 0; k < 8; ++k) {
            int idx = ((2 * k) & 63) | h;
            px[0][k] = __shfl(E0.x, idx);
            pw[0][k] = __int_as_float(__shfl(E0.y, idx));
        }
        #pragma unroll
        for (int k = 0; k < 8; ++k)
            u[0][k] = *reinterpret_cast<const unsigned*>(
                xw + (size_t)(px[0][k] & 0xFFFF) * XW_LD + (cp << 1));

        #pragma unroll
        for (int j = 0; j < 8; ++j) {
            const int cb = j & 1, nb = cb ^ 1;
            if (j + 1 < 8) {
                #pragma unroll
                for (int k = 0; k < 8; ++k) {
                    int t  = (j + 1) * 8 + k;
                    int sx = (t < 32) ? E0.x : E1.x;
                    int sy = (t < 32) ? E0.y : E1.y;
                    int idx = ((2 * t) & 63) | h;
                    px[nb][k] = __shfl(sx, idx);
                    pw[nb][k] = __int_as_float(__shfl(sy, idx));
                }
                #pragma unroll
                for (int k = 0; k < 8; ++k)
                    u[nb][k] = *reinterpret_cast<const unsigned*>(
                        xw + (size_t)(px[nb][k] & 0xFFFF) * XW_LD + (cp << 1));
            }
            #pragma unroll
            for (int k = 0; k < 8; ++k) {
                int nd = (int)(((unsigned)px[cb][k]) >> 16);
                if (nd != cur) {                  // uniform within each half
                    if (act && cur >= 0) {
                        atomicAdd(&acc[cur & (BNODES - 1)][cp << 1],       ax);
                        atomicAdd(&acc[cur & (BNODES - 1)][(cp << 1) + 1], ay);
                    }
                    ax = 0.f; ay = 0.f; cur = nd;
                }
                float    wf = pw[cb][k];
                unsigned uu = u[cb][k];
                ax = fmaf(wf, bf2f(uu & 0xFFFFu), ax);
                ay = fmaf(wf, bf2f(uu >> 16), ay);
            }
        }
    }
    // tail: per-edge (same parity split)
    for (int j = i + h; j < myHi; j += 2) {
        int2 M = epack[j];
        int nd = (int)(((unsigned)M.x) >> 16);
        if (nd != cur) {
            if (act && cur >= 0) {
                atomicAdd(&acc[cur & (BNODES - 1)][cp << 1],       ax);
                atomicAdd(&acc[cur & (BNODES - 1)][(cp << 1) + 1], ay);
            }
            ax = 0.f; ay = 0.f; cur = nd;
        }
        unsigned R = *reinterpret_cast<const unsigned*>(
            xw + (size_t)(M.x & 0xFFFF) * XW_LD + (cp << 1));
        float wf = __int_as_float(M.y);
        ax = fmaf(wf, bf2f(R & 0xFFFFu), ax);
        ay = fmaf(wf, bf2f(R >> 16), ay);
    }
    if (act && cur >= 0) {
        atomicAdd(&acc[cur & (BNODES - 1)][cp << 1],       ax);
        atomicAdd(&acc[cur & (BNODES - 1)][(cp << 1) + 1], ay);
    }
    __syncthreads();

    // epilogue: bias + log-softmax per node (8 nodes per wave), plain stores
    bool ch = (lane < OUT_CH);
    float bv = ch ? bias[lane] : 0.f;
    int node0 = b << BSHIFT;
    for (int n = wid; n < BNODES; n += 8) {
        int node = node0 + n;
        if (node >= N_NODES) break;
        float v = ch ? (acc[n][lane] + bv) : -INFINITY;
        float m = v;
        #pragma unroll
        for (int d = 32; d >= 1; d >>= 1) m = fmaxf(m, __shfl_xor(m, d));
        float e = ch ? expf(v - m) : 0.f;
        float s = e;
        #pragma unroll
        for (int d = 32; d >= 1; d >>= 1) s += __shfl_xor(s, d);
        float lse = m + logf(s);
        if (ch) out[(size_t)node * OUT_CH + lane] = v - lse;
    }
}

extern "C" void kernel_launch(void* const* d_in, const int* in_sizes, int n_in,
                              void* d_out, int out_size, void* d_ws, size_t ws_size,
                              hipStream_t stream) {
    const int*   edge_index = (const int*)d_in[0];
    const float* features   = (const float*)d_in[1];
    const float* eweights   = (const float*)d_in[2];
    const float* weight     = (const float*)d_in[3];
    const float* bias       = (const float*)d_in[4];

    const int* src = edge_index;            // edge_index[0, :]
    const int* dst = edge_index + N_EDGES;  // edge_index[1, :]

    float* out = (float*)d_out;

    // Workspace layout (bytes):
    //   xw (bf16, LD=64) @ 0 : 50000*64*2 = 6,400,000
    //   counts  @ 9,600,000 : NB*4
    //   base    @ 9,616,000 : NB*4
    //   cursor  @ 9,632,000 : NB*4
    //   epack   @ 9,648,000 : 12,800,000   (ends 22,448,000)
    //   wfrag   @ 22,448,000 : 49,152
    char* ws = (char*)d_ws;
    unsigned short* xw    = (unsigned short*)(ws + 0);
    int*   counts = (int*)  (ws + 9600000);
    int*   base   = (int*)  (ws + 9616000);
    int*   cursor = (int*)  (ws + 9632000);
    int2*  epack  = (int2*) (ws + 9648000);
    unsigned short* wfrag = (unsigned short*)(ws + 22448000);

    hipMemsetAsync(counts, 0, NB * sizeof(int), stream);

    // 0) pre-format B fragments (once per launch)
    prep_bfrag<<<(IN_CH * OUT_CH / 4 + 255) / 256, 256, 0, stream>>>(weight, wfrag);

    // 1) gemm (bf16 MFMA) and dst-histogram, concurrent in one launch
    gemm_hist<<<GEMM_BLOCKS + HIST_BLOCKS, 256, 0, stream>>>(features, wfrag, xw,
                                                             dst, counts);

    // 2) scan + bucket binning (coarse, write-coalesced) + in-bucket sort
    bucket_scan<<<1, 1024, 0, stream>>>(counts, base, cursor);
    bin_edges<<<(N_EDGES + ETILE - 1) / ETILE, 512, 0, stream>>>(src, dst, eweights,
                                                                 cursor, epack);
    sort_bucket<<<NB, 256, 0, stream>>>(base, cursor, epack);

    // 3) per-bucket aggregate (LDS boundary-flush) + bias + log-softmax
    bucket_agg_lsm<<<NB, 512, 0, stream>>>(base, cursor, epack, xw, bias, out);
}

// Round 19
// 175.564 us; speedup vs baseline: 3.0420x; 1.0315x over previous
//
#include <hip/hip_runtime.h>
#include <math.h>

#define N_NODES 50000
#define N_EDGES 1600000
#define IN_CH   512
#define OUT_CH  48
#define XW_LD   64                   // xw row stride in ushorts -> 128B, one cache line
#define N_TILES (N_NODES / 16)       // 3125 row-tiles, exact

#define BSHIFT  6                    // 64 nodes per bucket
#define BNODES  64
#define NB      ((N_NODES + BNODES - 1) / BNODES)   // 782 buckets
#define ETILE   8192                 // edges per bin_edges block
#define CAP     2816                 // max edges per bucket handled by sort (mean 2046)

#define BFRAG_SHORTS (16 * 3 * 64 * 8)   // 24576 shorts = 48 KB fragment image of B
#define GEMM_BLOCKS ((N_TILES + 3) / 4)  // 782
#define HIST_BLOCKS 256

typedef __attribute__((ext_vector_type(8))) short bf16x8;
typedef __attribute__((ext_vector_type(4))) float f32x4;

// fp32 -> bf16 (round-to-nearest-even), branch-free
static __device__ inline short f2bf(float x) {
    union { float f; unsigned u; } in; in.f = x;
    unsigned r = in.u + 0x7fffu + ((in.u >> 16) & 1u);
    return (short)(r >> 16);
}
static __device__ inline float bf2f(unsigned v16) {
    union { unsigned u; float f; } o; o.u = v16 << 16; return o.f;
}

// ---------------- Kernel 0: pre-format B into MFMA fragment layout (once) ----------------
__global__ __launch_bounds__(256) void prep_bfrag(const float* __restrict__ w,
                                                  unsigned short* __restrict__ wfrag) {
    int i = blockIdx.x * blockDim.x + threadIdx.x;       // one float4 per thread
    if (i >= IN_CH * OUT_CH / 4) return;
    int flat = i * 4;
    int k   = flat / OUT_CH;
    int col = flat % OUT_CH;
    float4 v = *reinterpret_cast<const float4*>(w + flat);
    int s = k >> 5, j = k & 7, q = (k >> 3) & 3;
    float vv[4] = {v.x, v.y, v.z, v.w};
    #pragma unroll
    for (int c = 0; c < 4; ++c) {
        int cc = col + c;
        int t  = cc >> 4;
        int ln = (cc & 15) | (q << 4);
        wfrag[((s * 3 + t) * 64 + ln) * 8 + j] = (unsigned short)f2bf(vv[c]);
    }
}

// ---------------- Kernel 1 (merged): gemm blocks + hist blocks ----------------
static __device__ void gemm_body(char* smem, const float* __restrict__ f,
                                 const unsigned short* __restrict__ wfrag,
                                 unsigned short* __restrict__ xw) {
    short* sBl = reinterpret_cast<short*>(smem);

    int tid  = threadIdx.x;
    int lane = tid & 63;
    int wid  = tid >> 6;

    {
        const uint4* gw = reinterpret_cast<const uint4*>(wfrag);
        uint4*       sw = reinterpret_cast<uint4*>(smem);
        #pragma unroll
        for (int i = 0; i < BFRAG_SHORTS / 8 / 256; ++i)   // 12 iterations
            sw[i * 256 + tid] = gw[i * 256 + tid];
    }
    __syncthreads();

    int tile = blockIdx.x * 4 + wid;
    if (tile >= N_TILES) return;

    const bf16x8* sB = reinterpret_cast<const bf16x8*>(sBl);

    int row = tile * 16 + (lane & 15);
    const float* fp = f + (size_t)row * IN_CH + ((lane >> 4) << 3);

    f32x4 acc0 = {0.f, 0.f, 0.f, 0.f};
    f32x4 acc1 = {0.f, 0.f, 0.f, 0.f};
    f32x4 acc2 = {0.f, 0.f, 0.f, 0.f};

    float4 a0[2], a1[2];
    a0[0] = *reinterpret_cast<const float4*>(fp);
    a1[0] = *reinterpret_cast<const float4*>(fp + 4);

    #pragma unroll
    for (int s = 0; s < 16; ++s) {
        const int cb = s & 1, nb = cb ^ 1;
        if (s + 1 < 16) {                                  // prefetch next K-step
            a0[nb] = *reinterpret_cast<const float4*>(fp + (s + 1) * 32);
            a1[nb] = *reinterpret_cast<const float4*>(fp + (s + 1) * 32 + 4);
        }
        bf16x8 a;
        a[0] = f2bf(a0[cb].x); a[1] = f2bf(a0[cb].y);
        a[2] = f2bf(a0[cb].z); a[3] = f2bf(a0[cb].w);
        a[4] = f2bf(a1[cb].x); a[5] = f2bf(a1[cb].y);
        a[6] = f2bf(a1[cb].z); a[7] = f2bf(a1[cb].w);
        bf16x8 b0 = sB[(s * 3 + 0) * 64 + lane];
        bf16x8 b1 = sB[(s * 3 + 1) * 64 + lane];
        bf16x8 b2 = sB[(s * 3 + 2) * 64 + lane];
        acc0 = __builtin_amdgcn_mfma_f32_16x16x32_bf16(a, b0, acc0, 0, 0, 0);
        acc1 = __builtin_amdgcn_mfma_f32_16x16x32_bf16(a, b1, acc1, 0, 0, 0);
        acc2 = __builtin_amdgcn_mfma_f32_16x16x32_bf16(a, b2, acc2, 0, 0, 0);
    }

    unsigned short* orow = xw + (size_t)tile * 16 * XW_LD;
    int c  = lane & 15;
    int r0 = (lane >> 4) * 4;
    #pragma unroll
    for (int r = 0; r < 4; ++r) {
        orow[(size_t)(r0 + r) * XW_LD +  0 + c] = (unsigned short)f2bf(acc0[r]);
        orow[(size_t)(r0 + r) * XW_LD + 16 + c] = (unsigned short)f2bf(acc1[r]);
        orow[(size_t)(r0 + r) * XW_LD + 32 + c] = (unsigned short)f2bf(acc2[r]);
    }
}

static __device__ void hist_body(char* smem, int bid, const int* __restrict__ dst,
                                 int* __restrict__ counts) {
    int* hc = reinterpret_cast<int*>(smem);
    for (int i = threadIdx.x; i < NB; i += 256) hc[i] = 0;
    __syncthreads();
    for (int e = bid * 256 + threadIdx.x; e < N_EDGES; e += HIST_BLOCKS * 256)
        atomicAdd(&hc[dst[e] >> BSHIFT], 1);
    __syncthreads();
    for (int i = threadIdx.x; i < NB; i += 256)
        if (hc[i]) atomicAdd(&counts[i], hc[i]);
}

__global__ __launch_bounds__(256) void gemm_hist(const float* __restrict__ f,
                                                 const unsigned short* __restrict__ wfrag,
                                                 unsigned short* __restrict__ xw,
                                                 const int* __restrict__ dst,
                                                 int* __restrict__ counts) {
    __shared__ __align__(16) char smem[BFRAG_SHORTS * 2];   // 48 KB union
    if (blockIdx.x < GEMM_BLOCKS) gemm_body(smem, f, wfrag, xw);
    else                          hist_body(smem, blockIdx.x - GEMM_BLOCKS, dst, counts);
}

// ---------------- Kernel 3: exclusive scan over NB buckets (1 block, 2/thread) ----------------
__global__ __launch_bounds__(1024) void bucket_scan(const int* __restrict__ counts,
                                                    int* __restrict__ base,
                                                    int* __restrict__ cursor) {
    __shared__ int sdata[1024];
    int t = threadIdx.x;
    int i0 = 2 * t, i1 = 2 * t + 1;
    int v0 = (i0 < NB) ? counts[i0] : 0;
    int v1 = (i1 < NB) ? counts[i1] : 0;
    int s = v0 + v1;
    sdata[t] = s;
    __syncthreads();
    for (int d = 1; d < 1024; d <<= 1) {
        int x = (t >= d) ? sdata[t - d] : 0;
        __syncthreads();
        sdata[t] += x;
        __syncthreads();
    }
    int excl = sdata[t] - s;
    if (i0 < NB) { base[i0] = excl;      cursor[i0] = excl; }
    if (i1 < NB) { base[i1] = excl + v0; cursor[i1] = excl + v0; }
}

// ---------------- Kernel 4: LDS-staged binning (coalesced scatter) ----------------
__global__ __launch_bounds__(512) void bin_edges(const int* __restrict__ src,
                                                 const int* __restrict__ dst,
                                                 const float* __restrict__ ew,
                                                 int* __restrict__ cursor,
                                                 int2* __restrict__ epack) {
    __shared__ int   hist[NB];
    __shared__ int   loff[NB];
    __shared__ int   gbase[NB];
    __shared__ int   ssum[512];
    __shared__ int2  buf[ETILE];      // 64 KB
    __shared__ short bkt[ETILE];      // 16 KB

    int tid = threadIdx.x;
    int tileStart = blockIdx.x * ETILE;
    int tileN = N_EDGES - tileStart; if (tileN > ETILE) tileN = ETILE;

    for (int i = tid; i < NB; i += 512) hist[i] = 0;
    __syncthreads();

    // pass A: ranks via LDS histogram (cache dst in registers)
    int rank[ETILE / 512];
    int dreg[ETILE / 512];
    #pragma unroll
    for (int k = 0; k < ETILE / 512; ++k) {
        int e = tileStart + k * 512 + tid;
        dreg[k] = (e < N_EDGES) ? dst[e] : 0;
        rank[k] = (e < N_EDGES) ? atomicAdd(&hist[dreg[k] >> BSHIFT], 1) : 0;
    }
    __syncthreads();

    // reserve global space per bucket
    for (int i = tid; i < NB; i += 512) {
        int c = hist[i];
        gbase[i] = c ? atomicAdd(&cursor[i], c) : 0;
    }

    // exclusive scan of hist -> loff (4 entries per thread)
    int a[4], lsum = 0;
    #pragma unroll
    for (int c = 0; c < 4; ++c) {
        int idx = 4 * tid + c;
        a[c] = (idx < NB) ? hist[idx] : 0;
        lsum += a[c];
    }
    ssum[tid] = lsum;
    __syncthreads();
    for (int d = 1; d < 512; d <<= 1) {
        int x = (tid >= d) ? ssum[tid - d] : 0;
        __syncthreads();
        ssum[tid] += x;
        __syncthreads();
    }
    int excl = ssum[tid] - lsum;
    #pragma unroll
    for (int c = 0; c < 4; ++c) {
        int idx = 4 * tid + c;
        if (idx < NB) { loff[idx] = excl; excl += a[c]; }
    }
    __syncthreads();

    // pass B: stage edges into LDS in bucket order
    #pragma unroll
    for (int k = 0; k < ETILE / 512; ++k) {
        int e = tileStart + k * 512 + tid;
        if (e < N_EDGES) {
            int d = dreg[k];
            int b = d >> BSHIFT;
            int slot = loff[b] + rank[k];
            int2 p;
            p.x = (src[e] & 0xFFFF) | (d << 16);   // src 16b | full dst 16b
            p.y = __float_as_int(ew[e]);
            buf[slot] = p;
            bkt[slot] = (short)b;
        }
    }
    __syncthreads();

    // streaming writeout: consecutive slots -> consecutive global positions
    for (int idx = tid; idx < tileN; idx += 512) {
        int b = bkt[idx];
        epack[gbase[b] + idx - loff[b]] = buf[idx];
    }
}

// ---------------- Kernel 5: in-bucket sort by node ----------------
__global__ __launch_bounds__(256) void sort_bucket(const int* __restrict__ base,
                                                   const int* __restrict__ cursor,
                                                   int2* __restrict__ epack) {
    __shared__ int2  A[CAP];      // 22.5 KB
    __shared__ int2  B[CAP];      // 22.5 KB
    __shared__ short rk[CAP];     // 5.6 KB
    __shared__ int   hist[BNODES];
    __shared__ int   loff[BNODES];

    int b  = blockIdx.x;
    int lo = base[b], hi = cursor[b];
    int len = hi - lo;
    if (len <= 0 || len > CAP) return;   // oversize: leave unsorted (agg still correct)

    int tid = threadIdx.x;
    if (tid < BNODES) hist[tid] = 0;
    for (int i = tid; i < len; i += 256) A[i] = epack[lo + i];
    __syncthreads();

    for (int i = tid; i < len; i += 256) {
        int key = (((unsigned)A[i].x) >> 16) & (BNODES - 1);
        rk[i] = (short)atomicAdd(&hist[key], 1);
    }
    __syncthreads();

    if (tid < BNODES) {           // wave 0: exclusive scan of 64 counters
        int v = hist[tid];
        int s = v;
        #pragma unroll
        for (int d = 1; d < 64; d <<= 1) {
            int t = __shfl_up(s, d);
            if (tid >= d) s += t;
        }
        loff[tid] = s - v;
    }
    __syncthreads();

    for (int i = tid; i < len; i += 256) {
        int key = (((unsigned)A[i].x) >> 16) & (BNODES - 1);
        B[loff[key] + rk[i]] = A[i];
    }
    __syncthreads();

    for (int i = tid; i < len; i += 256) epack[lo + i] = B[i];
}

// ---------------- Kernel 6: per-bucket aggregate + bias + log-softmax ----------------
// One 512-thread block (8 waves) per 64-node bucket. NO forced occupancy:
// plain launch_bounds(512) lets the pipeline arrays stay in registers
// (r18's (512,8) capped VGPR at 32 -> scratch spill -> 174MB FETCH / 92MB WRITE).
__global__ __launch_bounds__(512) void bucket_agg_lsm(
        const int* __restrict__ base, const int* __restrict__ cursor,
        const int2* __restrict__ epack, const unsigned short* __restrict__ xw,
        const float* __restrict__ bias, float* __restrict__ out) {
    __shared__ float acc[BNODES][OUT_CH];   // 12 KB

    int b   = blockIdx.x;
    int tid = threadIdx.x, lane = tid & 63, wid = tid >> 6;   // 8 waves

    for (int i = tid; i < BNODES * OUT_CH; i += 512)
        reinterpret_cast<float*>(acc)[i] = 0.f;
    __syncthreads();

    int lo = base[b], hi = cursor[b];
    int len = hi - lo;
    int per = (len + 7) >> 3;
    int myLo = lo + wid * per;
    int myHi = myLo + per; if (myHi > hi) myHi = hi;

    int h  = lane >> 5;                   // half: even / odd edges
    int cp = lane & 31;                   // channel pair (cp<24 real)
    bool act = (cp < 24);

    float ax = 0.f, ay = 0.f;
    int cur = -1;

    int i = myLo;
    for (; i + 128 <= myHi; i += 128) {
        int2 E0 = epack[i + lane];
        int2 E1 = epack[i + 64 + lane];

        int px[2][8]; float pw[2][8]; unsigned u[2][8];

        #pragma unroll
        for (int k = 0; k < 8; ++k) {
            int idx = ((2 * k) & 63) | h;
            px[0][k] = __shfl(E0.x, idx);
            pw[0][k] = __int_as_float(__shfl(E0.y, idx));
        }
        #pragma unroll
        for (int k = 0; k < 8; ++k)
            u[0][k] = *reinterpret_cast<const unsigned*>(
                xw + (size_t)(px[0][k] & 0xFFFF) * XW_LD + (cp << 1));

        #pragma unroll
        for (int j = 0; j < 8; ++j) {
            const int cb = j & 1, nb = cb ^ 1;
            if (j + 1 < 8) {
                #pragma unroll
                for (int k = 0; k < 8; ++k) {
                    int t  = (j + 1) * 8 + k;
                    int sx = (t < 32) ? E0.x : E1.x;
                    int sy = (t < 32) ? E0.y : E1.y;
                    int idx = ((2 * t) & 63) | h;
                    px[nb][k] = __shfl(sx, idx);
                    pw[nb][k] = __int_as_float(__shfl(sy, idx));
                }
                #pragma unroll
                for (int k = 0; k < 8; ++k)
                    u[nb][k] = *reinterpret_cast<const unsigned*>(
                        xw + (size_t)(px[nb][k] & 0xFFFF) * XW_LD + (cp << 1));
            }
            #pragma unroll
            for (int k = 0; k < 8; ++k) {
                int nd = (int)(((unsigned)px[cb][k]) >> 16);
                if (nd != cur) {                  // uniform within each half
                    if (act && cur >= 0) {
                        atomicAdd(&acc[cur & (BNODES - 1)][cp << 1],       ax);
                        atomicAdd(&acc[cur & (BNODES - 1)][(cp << 1) + 1], ay);
                    }
                    ax = 0.f; ay = 0.f; cur = nd;
                }
                float    wf = pw[cb][k];
                unsigned uu = u[cb][k];
                ax = fmaf(wf, bf2f(uu & 0xFFFFu), ax);
                ay = fmaf(wf, bf2f(uu >> 16), ay);
            }
        }
    }
    // tail: per-edge (same parity split)
    for (int j = i + h; j < myHi; j += 2) {
        int2 M = epack[j];
        int nd = (int)(((unsigned)M.x) >> 16);
        if (nd != cur) {
            if (act && cur >= 0) {
                atomicAdd(&acc[cur & (BNODES - 1)][cp << 1],       ax);
                atomicAdd(&acc[cur & (BNODES - 1)][(cp << 1) + 1], ay);
            }
            ax = 0.f; ay = 0.f; cur = nd;
        }
        unsigned R = *reinterpret_cast<const unsigned*>(
            xw + (size_t)(M.x & 0xFFFF) * XW_LD + (cp << 1));
        float wf = __int_as_float(M.y);
        ax = fmaf(wf, bf2f(R & 0xFFFFu), ax);
        ay = fmaf(wf, bf2f(R >> 16), ay);
    }
    if (act && cur >= 0) {
        atomicAdd(&acc[cur & (BNODES - 1)][cp << 1],       ax);
        atomicAdd(&acc[cur & (BNODES - 1)][(cp << 1) + 1], ay);
    }
    __syncthreads();

    // epilogue: bias + log-softmax per node (8 nodes per wave), plain stores
    bool ch = (lane < OUT_CH);
    float bv = ch ? bias[lane] : 0.f;
    int node0 = b << BSHIFT;
    for (int n = wid; n < BNODES; n += 8) {
        int node = node0 + n;
        if (node >= N_NODES) break;
        float v = ch ? (acc[n][lane] + bv) : -INFINITY;
        float m = v;
        #pragma unroll
        for (int d = 32; d >= 1; d >>= 1) m = fmaxf(m, __shfl_xor(m, d));
        float e = ch ? expf(v - m) : 0.f;
        float s = e;
        #pragma unroll
        for (int d = 32; d >= 1; d >>= 1) s += __shfl_xor(s, d);
        float lse = m + logf(s);
        if (ch) out[(size_t)node * OUT_CH + lane] = v - lse;
    }
}

extern "C" void kernel_launch(void* const* d_in, const int* in_sizes, int n_in,
                              void* d_out, int out_size, void* d_ws, size_t ws_size,
                              hipStream_t stream) {
    const int*   edge_index = (const int*)d_in[0];
    const float* features   = (const float*)d_in[1];
    const float* eweights   = (const float*)d_in[2];
    const float* weight     = (const float*)d_in[3];
    const float* bias       = (const float*)d_in[4];

    const int* src = edge_index;            // edge_index[0, :]
    const int* dst = edge_index + N_EDGES;  // edge_index[1, :]

    float* out = (float*)d_out;

    // Workspace layout (bytes):
    //   xw (bf16, LD=64) @ 0 : 50000*64*2 = 6,400,000
    //   counts  @ 9,600,000 : NB*4
    //   base    @ 9,616,000 : NB*4
    //   cursor  @ 9,632,000 : NB*4
    //   epack   @ 9,648,000 : 12,800,000   (ends 22,448,000)
    //   wfrag   @ 22,448,000 : 49,152
    char* ws = (char*)d_ws;
    unsigned short* xw    = (unsigned short*)(ws + 0);
    int*   counts = (int*)  (ws + 9600000);
    int*   base   = (int*)  (ws + 9616000);
    int*   cursor = (int*)  (ws + 9632000);
    int2*  epack  = (int2*) (ws + 9648000);
    unsigned short* wfrag = (unsigned short*)(ws + 22448000);

    hipMemsetAsync(counts, 0, NB * sizeof(int), stream);

    // 0) pre-format B fragments (once per launch)
    prep_bfrag<<<(IN_CH * OUT_CH / 4 + 255) / 256, 256, 0, stream>>>(weight, wfrag);

    // 1) gemm (bf16 MFMA) and dst-histogram, concurrent in one launch
    gemm_hist<<<GEMM_BLOCKS + HIST_BLOCKS, 256, 0, stream>>>(features, wfrag, xw,
                                                             dst, counts);

    // 2) scan + bucket binning (coarse, write-coalesced) + in-bucket sort
    bucket_scan<<<1, 1024, 0, stream>>>(counts, base, cursor);
    bin_edges<<<(N_EDGES + ETILE - 1) / ETILE, 512, 0, stream>>>(src, dst, eweights,
                                                                 cursor, epack);
    sort_bucket<<<NB, 256, 0, stream>>>(base, cursor, epack);

    // 3) per-bucket aggregate (LDS boundary-flush) + bias + log-softmax
    bucket_agg_lsm<<<NB, 512, 0, stream>>>(base, cursor, epack, xw, bias, out);
}

// Round 20
// 147.607 us; speedup vs baseline: 3.6182x; 1.1894x over previous
//
#include <hip/hip_runtime.h>
#include <math.h>

#define N_NODES 50000
#define N_EDGES 1600000
#define IN_CH   512
#define OUT_CH  48
#define XW_LD   64                   // xw row stride in ushorts -> 128B, one cache line
#define N_TILES (N_NODES / 16)       // 3125 row-tiles, exact

#define BSHIFT  6                    // 64 nodes per bucket
#define BNODES  64
#define NB      ((N_NODES + BNODES - 1) / BNODES)   // 782 buckets
#define ETILE   8192                 // edges per bin_edges block
#define CAP     2816                 // max edges per bucket handled by sort (mean 2046)
#define CHUNK   128                  // edges per wave in seg_aggregate (divides N_EDGES)

#define BFRAG_SHORTS (16 * 3 * 64 * 8)   // 24576 shorts = 48 KB fragment image of B
#define GEMM_BLOCKS ((N_TILES + 3) / 4)  // 782
#define HIST_BLOCKS 256

typedef __attribute__((ext_vector_type(8))) short bf16x8;
typedef __attribute__((ext_vector_type(4))) float f32x4;

// fp32 -> bf16 (round-to-nearest-even), branch-free
static __device__ inline short f2bf(float x) {
    union { float f; unsigned u; } in; in.f = x;
    unsigned r = in.u + 0x7fffu + ((in.u >> 16) & 1u);
    return (short)(r >> 16);
}
static __device__ inline float bf2f(unsigned v16) {
    union { unsigned u; float f; } o; o.u = v16 << 16; return o.f;
}

// ---------------- Kernel 0: pre-format B into MFMA fragment layout (once) ----------------
__global__ __launch_bounds__(256) void prep_bfrag(const float* __restrict__ w,
                                                  unsigned short* __restrict__ wfrag) {
    int i = blockIdx.x * blockDim.x + threadIdx.x;       // one float4 per thread
    if (i >= IN_CH * OUT_CH / 4) return;
    int flat = i * 4;
    int k   = flat / OUT_CH;
    int col = flat % OUT_CH;
    float4 v = *reinterpret_cast<const float4*>(w + flat);
    int s = k >> 5, j = k & 7, q = (k >> 3) & 3;
    float vv[4] = {v.x, v.y, v.z, v.w};
    #pragma unroll
    for (int c = 0; c < 4; ++c) {
        int cc = col + c;
        int t  = cc >> 4;
        int ln = (cc & 15) | (q << 4);
        wfrag[((s * 3 + t) * 64 + ln) * 8 + j] = (unsigned short)f2bf(vv[c]);
    }
}

// ---------------- Kernel 1 (merged): gemm blocks + hist blocks ----------------
static __device__ void gemm_body(char* smem, const float* __restrict__ f,
                                 const unsigned short* __restrict__ wfrag,
                                 unsigned short* __restrict__ xw) {
    short* sBl = reinterpret_cast<short*>(smem);

    int tid  = threadIdx.x;
    int lane = tid & 63;
    int wid  = tid >> 6;

    {
        const uint4* gw = reinterpret_cast<const uint4*>(wfrag);
        uint4*       sw = reinterpret_cast<uint4*>(smem);
        #pragma unroll
        for (int i = 0; i < BFRAG_SHORTS / 8 / 256; ++i)   // 12 iterations
            sw[i * 256 + tid] = gw[i * 256 + tid];
    }
    __syncthreads();

    int tile = blockIdx.x * 4 + wid;
    if (tile >= N_TILES) return;

    const bf16x8* sB = reinterpret_cast<const bf16x8*>(sBl);

    int row = tile * 16 + (lane & 15);
    const float* fp = f + (size_t)row * IN_CH + ((lane >> 4) << 3);

    f32x4 acc0 = {0.f, 0.f, 0.f, 0.f};
    f32x4 acc1 = {0.f, 0.f, 0.f, 0.f};
    f32x4 acc2 = {0.f, 0.f, 0.f, 0.f};

    float4 a0[2], a1[2];
    a0[0] = *reinterpret_cast<const float4*>(fp);
    a1[0] = *reinterpret_cast<const float4*>(fp + 4);

    #pragma unroll
    for (int s = 0; s < 16; ++s) {
        const int cb = s & 1, nb = cb ^ 1;
        if (s + 1 < 16) {                                  // prefetch next K-step
            a0[nb] = *reinterpret_cast<const float4*>(fp + (s + 1) * 32);
            a1[nb] = *reinterpret_cast<const float4*>(fp + (s + 1) * 32 + 4);
        }
        bf16x8 a;
        a[0] = f2bf(a0[cb].x); a[1] = f2bf(a0[cb].y);
        a[2] = f2bf(a0[cb].z); a[3] = f2bf(a0[cb].w);
        a[4] = f2bf(a1[cb].x); a[5] = f2bf(a1[cb].y);
        a[6] = f2bf(a1[cb].z); a[7] = f2bf(a1[cb].w);
        bf16x8 b0 = sB[(s * 3 + 0) * 64 + lane];
        bf16x8 b1 = sB[(s * 3 + 1) * 64 + lane];
        bf16x8 b2 = sB[(s * 3 + 2) * 64 + lane];
        acc0 = __builtin_amdgcn_mfma_f32_16x16x32_bf16(a, b0, acc0, 0, 0, 0);
        acc1 = __builtin_amdgcn_mfma_f32_16x16x32_bf16(a, b1, acc1, 0, 0, 0);
        acc2 = __builtin_amdgcn_mfma_f32_16x16x32_bf16(a, b2, acc2, 0, 0, 0);
    }

    unsigned short* orow = xw + (size_t)tile * 16 * XW_LD;
    int c  = lane & 15;
    int r0 = (lane >> 4) * 4;
    #pragma unroll
    for (int r = 0; r < 4; ++r) {
        orow[(size_t)(r0 + r) * XW_LD +  0 + c] = (unsigned short)f2bf(acc0[r]);
        orow[(size_t)(r0 + r) * XW_LD + 16 + c] = (unsigned short)f2bf(acc1[r]);
        orow[(size_t)(r0 + r) * XW_LD + 32 + c] = (unsigned short)f2bf(acc2[r]);
    }
}

static __device__ void hist_body(char* smem, int bid, const int* __restrict__ dst,
                                 int* __restrict__ counts) {
    int* hc = reinterpret_cast<int*>(smem);
    for (int i = threadIdx.x; i < NB; i += 256) hc[i] = 0;
    __syncthreads();
    for (int e = bid * 256 + threadIdx.x; e < N_EDGES; e += HIST_BLOCKS * 256)
        atomicAdd(&hc[dst[e] >> BSHIFT], 1);
    __syncthreads();
    for (int i = threadIdx.x; i < NB; i += 256)
        if (hc[i]) atomicAdd(&counts[i], hc[i]);
}

__global__ __launch_bounds__(256) void gemm_hist(const float* __restrict__ f,
                                                 const unsigned short* __restrict__ wfrag,
                                                 unsigned short* __restrict__ xw,
                                                 const int* __restrict__ dst,
                                                 int* __restrict__ counts) {
    __shared__ __align__(16) char smem[BFRAG_SHORTS * 2];   // 48 KB union
    if (blockIdx.x < GEMM_BLOCKS) gemm_body(smem, f, wfrag, xw);
    else                          hist_body(smem, blockIdx.x - GEMM_BLOCKS, dst, counts);
}

// ---------------- Kernel 3: exclusive scan over NB buckets (1 block, 2/thread) ----------------
__global__ __launch_bounds__(1024) void bucket_scan(const int* __restrict__ counts,
                                                    int* __restrict__ base,
                                                    int* __restrict__ cursor) {
    __shared__ int sdata[1024];
    int t = threadIdx.x;
    int i0 = 2 * t, i1 = 2 * t + 1;
    int v0 = (i0 < NB) ? counts[i0] : 0;
    int v1 = (i1 < NB) ? counts[i1] : 0;
    int s = v0 + v1;
    sdata[t] = s;
    __syncthreads();
    for (int d = 1; d < 1024; d <<= 1) {
        int x = (t >= d) ? sdata[t - d] : 0;
        __syncthreads();
        sdata[t] += x;
        __syncthreads();
    }
    int excl = sdata[t] - s;
    if (i0 < NB) { base[i0] = excl;      cursor[i0] = excl; }
    if (i1 < NB) { base[i1] = excl + v0; cursor[i1] = excl + v0; }
}

// ---------------- Kernel 4: LDS-staged binning (coalesced scatter) ----------------
__global__ __launch_bounds__(512) void bin_edges(const int* __restrict__ src,
                                                 const int* __restrict__ dst,
                                                 const float* __restrict__ ew,
                                                 int* __restrict__ cursor,
                                                 int2* __restrict__ epack) {
    __shared__ int   hist[NB];
    __shared__ int   loff[NB];
    __shared__ int   gbase[NB];
    __shared__ int   ssum[512];
    __shared__ int2  buf[ETILE];      // 64 KB
    __shared__ short bkt[ETILE];      // 16 KB

    int tid = threadIdx.x;
    int tileStart = blockIdx.x * ETILE;
    int tileN = N_EDGES - tileStart; if (tileN > ETILE) tileN = ETILE;

    for (int i = tid; i < NB; i += 512) hist[i] = 0;
    __syncthreads();

    // pass A: ranks via LDS histogram (cache dst in registers)
    int rank[ETILE / 512];
    int dreg[ETILE / 512];
    #pragma unroll
    for (int k = 0; k < ETILE / 512; ++k) {
        int e = tileStart + k * 512 + tid;
        dreg[k] = (e < N_EDGES) ? dst[e] : 0;
        rank[k] = (e < N_EDGES) ? atomicAdd(&hist[dreg[k] >> BSHIFT], 1) : 0;
    }
    __syncthreads();

    // reserve global space per bucket
    for (int i = tid; i < NB; i += 512) {
        int c = hist[i];
        gbase[i] = c ? atomicAdd(&cursor[i], c) : 0;
    }

    // exclusive scan of hist -> loff (4 entries per thread)
    int a[4], lsum = 0;
    #pragma unroll
    for (int c = 0; c < 4; ++c) {
        int idx = 4 * tid + c;
        a[c] = (idx < NB) ? hist[idx] : 0;
        lsum += a[c];
    }
    ssum[tid] = lsum;
    __syncthreads();
    for (int d = 1; d < 512; d <<= 1) {
        int x = (tid >= d) ? ssum[tid - d] : 0;
        __syncthreads();
        ssum[tid] += x;
        __syncthreads();
    }
    int excl = ssum[tid] - lsum;
    #pragma unroll
    for (int c = 0; c < 4; ++c) {
        int idx = 4 * tid + c;
        if (idx < NB) { loff[idx] = excl; excl += a[c]; }
    }
    __syncthreads();

    // pass B: stage edges into LDS in bucket order
    #pragma unroll
    for (int k = 0; k < ETILE / 512; ++k) {
        int e = tileStart + k * 512 + tid;
        if (e < N_EDGES) {
            int d = dreg[k];
            int b = d >> BSHIFT;
            int slot = loff[b] + rank[k];
            int2 p;
            p.x = (src[e] & 0xFFFF) | (d << 16);   // src 16b | full dst 16b
            p.y = __float_as_int(ew[e]);
            buf[slot] = p;
            bkt[slot] = (short)b;
        }
    }
    __syncthreads();

    // streaming writeout: consecutive slots -> consecutive global positions
    for (int idx = tid; idx < tileN; idx += 512) {
        int b = bkt[idx];
        epack[gbase[b] + idx - loff[b]] = buf[idx];
    }
}

// ---------------- Kernel 5: in-bucket sort by node ----------------
__global__ __launch_bounds__(256) void sort_bucket(const int* __restrict__ base,
                                                   const int* __restrict__ cursor,
                                                   int2* __restrict__ epack) {
    __shared__ int2  A[CAP];      // 22.5 KB
    __shared__ int2  B[CAP];      // 22.5 KB
    __shared__ short rk[CAP];     // 5.6 KB
    __shared__ int   hist[BNODES];
    __shared__ int   loff[BNODES];

    int b  = blockIdx.x;
    int lo = base[b], hi = cursor[b];
    int len = hi - lo;
    if (len <= 0 || len > CAP) return;   // oversize: leave unsorted (agg still correct)

    int tid = threadIdx.x;
    if (tid < BNODES) hist[tid] = 0;
    for (int i = tid; i < len; i += 256) A[i] = epack[lo + i];
    __syncthreads();

    for (int i = tid; i < len; i += 256) {
        int key = (((unsigned)A[i].x) >> 16) & (BNODES - 1);
        rk[i] = (short)atomicAdd(&hist[key], 1);
    }
    __syncthreads();

    if (tid < BNODES) {           // wave 0: exclusive scan of 64 counters
        int v = hist[tid];
        int s = v;
        #pragma unroll
        for (int d = 1; d < 64; d <<= 1) {
            int t = __shfl_up(s, d);
            if (tid >= d) s += t;
        }
        loff[tid] = s - v;
    }
    __syncthreads();

    for (int i = tid; i < len; i += 256) {
        int key = (((unsigned)A[i].x) >> 16) & (BNODES - 1);
        B[loff[key] + rk[i]] = A[i];
    }
    __syncthreads();

    for (int i = tid; i < len; i += 256) epack[lo + i] = B[i];
}

// ---------------- Kernel 6: segmented reduction over sorted edges ----------------
// Flat grid (3125 blocks x 256 thr), one wave per 128-edge chunk, TWO
// independent half-wave streams: half h = lane>=32 processes edges base+2t+h;
// cp = lane&31 is the channel pair (cp<24 real). One dword gather = 2 bf16
// channels, one line per edge; 8-deep double-buffered batches (compile-time
// indices). Run-boundary flush: global fp32 atomic pairs (rare, sorted order).
__global__ __launch_bounds__(256) void seg_aggregate(const int2* __restrict__ epack,
                                                     const unsigned short* __restrict__ xw,
                                                     float* __restrict__ out) {
    int wv   = (blockIdx.x * blockDim.x + threadIdx.x) >> 6;
    int lane = threadIdx.x & 63;
    int base = wv * CHUNK;
    if (base >= N_EDGES) return;          // CHUNK divides N_EDGES exactly
    int h  = lane >> 5;                   // half: 0 -> even edges, 1 -> odd edges
    int cp = lane & 31;                   // channel pair (cp<24 real, rest pad)
    bool act = (cp < 24);

    int2 E0 = epack[base + lane];
    int2 E1 = epack[base + 64 + lane];

    float ax = 0.f, ay = 0.f;
    int cur = ((unsigned)__shfl(E0.x, h)) >> 16;

    int px[2][8]; float pw[2][8]; unsigned u[2][8];

    #pragma unroll
    for (int k = 0; k < 8; ++k) {
        int idx = ((2 * k) & 63) | h;
        px[0][k] = __shfl(E0.x, idx);
        pw[0][k] = __int_as_float(__shfl(E0.y, idx));
    }
    #pragma unroll
    for (int k = 0; k < 8; ++k)
        u[0][k] = *reinterpret_cast<const unsigned*>(
            xw + (size_t)(px[0][k] & 0xFFFF) * XW_LD + (cp << 1));

    #pragma unroll
    for (int j = 0; j < 8; ++j) {
        const int cb = j & 1, nb = cb ^ 1;
        if (j + 1 < 8) {
            #pragma unroll
            for (int k = 0; k < 8; ++k) {
                int t  = (j + 1) * 8 + k;
                int sx = (t < 32) ? E0.x : E1.x;
                int sy = (t < 32) ? E0.y : E1.y;
                int idx = ((2 * t) & 63) | h;
                px[nb][k] = __shfl(sx, idx);
                pw[nb][k] = __int_as_float(__shfl(sy, idx));
            }
            #pragma unroll
            for (int k = 0; k < 8; ++k)
                u[nb][k] = *reinterpret_cast<const unsigned*>(
                    xw + (size_t)(px[nb][k] & 0xFFFF) * XW_LD + (cp << 1));
        }
        #pragma unroll
        for (int k = 0; k < 8; ++k) {
            int node = ((unsigned)px[cb][k]) >> 16;
            if (node != cur) {
                if (act) {
                    atomicAdd(&out[(size_t)cur * OUT_CH + (cp << 1)    ], ax);
                    atomicAdd(&out[(size_t)cur * OUT_CH + (cp << 1) + 1], ay);
                }
                ax = 0.f; ay = 0.f; cur = node;
            }
            float    wf = pw[cb][k];
            unsigned uu = u[cb][k];
            ax = fmaf(wf, bf2f(uu & 0xFFFFu), ax);
            ay = fmaf(wf, bf2f(uu >> 16), ay);
        }
    }

    if (act) {
        atomicAdd(&out[(size_t)cur * OUT_CH + (cp << 1)    ], ax);
        atomicAdd(&out[(size_t)cur * OUT_CH + (cp << 1) + 1], ay);
    }
}

// ---------------- Kernel 7: bias + log-softmax, in place, wave per node ----------------
__global__ __launch_bounds__(256) void lsm_rows(float* __restrict__ z,
                                                const float* __restrict__ bias) {
    int node = (blockIdx.x * blockDim.x + threadIdx.x) >> 6;
    int lane = threadIdx.x & 63;
    if (node >= N_NODES) return;
    bool ch = (lane < OUT_CH);

    float v = ch ? (z[(size_t)node * OUT_CH + lane] + bias[lane]) : -INFINITY;
    float m = v;
    #pragma unroll
    for (int d = 32; d >= 1; d >>= 1) m = fmaxf(m, __shfl_xor(m, d));
    float e = ch ? expf(v - m) : 0.f;
    float s = e;
    #pragma unroll
    for (int d = 32; d >= 1; d >>= 1) s += __shfl_xor(s, d);
    float lse = m + logf(s);
    if (ch) z[(size_t)node * OUT_CH + lane] = v - lse;
}

extern "C" void kernel_launch(void* const* d_in, const int* in_sizes, int n_in,
                              void* d_out, int out_size, void* d_ws, size_t ws_size,
                              hipStream_t stream) {
    const int*   edge_index = (const int*)d_in[0];
    const float* features   = (const float*)d_in[1];
    const float* eweights   = (const float*)d_in[2];
    const float* weight     = (const float*)d_in[3];
    const float* bias       = (const float*)d_in[4];

    const int* src = edge_index;            // edge_index[0, :]
    const int* dst = edge_index + N_EDGES;  // edge_index[1, :]

    float* out = (float*)d_out;

    // Workspace layout (bytes):
    //   xw (bf16, LD=64) @ 0 : 50000*64*2 = 6,400,000
    //   counts  @ 9,600,000 : NB*4
    //   base    @ 9,616,000 : NB*4
    //   cursor  @ 9,632,000 : NB*4
    //   epack   @ 9,648,000 : 12,800,000   (ends 22,448,000)
    //   wfrag   @ 22,448,000 : 49,152
    char* ws = (char*)d_ws;
    unsigned short* xw    = (unsigned short*)(ws + 0);
    int*   counts = (int*)  (ws + 9600000);
    int*   base   = (int*)  (ws + 9616000);
    int*   cursor = (int*)  (ws + 9632000);
    int2*  epack  = (int2*) (ws + 9648000);
    unsigned short* wfrag = (unsigned short*)(ws + 22448000);

    hipMemsetAsync(counts, 0, NB * sizeof(int), stream);
    hipMemsetAsync(d_out, 0, (size_t)N_NODES * OUT_CH * sizeof(float), stream);

    // 0) pre-format B fragments (once per launch)
    prep_bfrag<<<(IN_CH * OUT_CH / 4 + 255) / 256, 256, 0, stream>>>(weight, wfrag);

    // 1) gemm (bf16 MFMA) and dst-histogram, concurrent in one launch
    gemm_hist<<<GEMM_BLOCKS + HIST_BLOCKS, 256, 0, stream>>>(features, wfrag, xw,
                                                             dst, counts);

    // 2) scan + bucket binning (coarse, write-coalesced) + in-bucket sort
    bucket_scan<<<1, 1024, 0, stream>>>(counts, base, cursor);
    bin_edges<<<(N_EDGES + ETILE - 1) / ETILE, 512, 0, stream>>>(src, dst, eweights,
                                                                 cursor, epack);
    sort_bucket<<<NB, 256, 0, stream>>>(base, cursor, epack);

    // 3) segmented reduction (flat grid, wave per 128-edge chunk)
    {
        int nWaves  = N_EDGES / CHUNK;                 // 12500
        int nBlocks = (nWaves + 3) / 4;                // 3125
        seg_aggregate<<<nBlocks, 256, 0, stream>>>(epack, xw, out);
    }
    // 4) bias + log-softmax
    lsm_rows<<<(N_NODES + 3) / 4, 256, 0, stream>>>(out, bias);
}

// Round 21
// 145.857 us; speedup vs baseline: 3.6616x; 1.0120x over previous
//
#include <hip/hip_runtime.h>
#include <math.h>

#define N_NODES 50000
#define N_EDGES 1600000
#define IN_CH   512
#define OUT_CH  48
#define XW_LD   64                   // xw row stride in ushorts -> 128B, one cache line
#define N_TILES (N_NODES / 16)       // 3125 row-tiles, exact

#define BSHIFT  6                    // 64 nodes per bucket
#define BNODES  64
#define NB      ((N_NODES + BNODES - 1) / BNODES)   // 782 buckets
#define ETILE   4096                 // edges per bin_edges block (391 blocks)
#define CAP     2816                 // max edges per bucket handled by sort (mean 2046)
#define CHUNK   128                  // edges per wave in seg_aggregate (divides N_EDGES)

#define BFRAG_SHORTS (16 * 3 * 64 * 8)   // 24576 shorts = 48 KB fragment image of B
#define GEMM_BLOCKS ((N_TILES + 3) / 4)  // 782
#define HIST_BLOCKS 256

typedef __attribute__((ext_vector_type(8))) short bf16x8;
typedef __attribute__((ext_vector_type(4))) float f32x4;

// fp32 -> bf16 (round-to-nearest-even), branch-free
static __device__ inline short f2bf(float x) {
    union { float f; unsigned u; } in; in.f = x;
    unsigned r = in.u + 0x7fffu + ((in.u >> 16) & 1u);
    return (short)(r >> 16);
}
static __device__ inline float bf2f(unsigned v16) {
    union { unsigned u; float f; } o; o.u = v16 << 16; return o.f;
}

// ---------------- Kernel 0: pre-format B into MFMA fragment layout (once) ----------------
__global__ __launch_bounds__(256) void prep_bfrag(const float* __restrict__ w,
                                                  unsigned short* __restrict__ wfrag) {
    int i = blockIdx.x * blockDim.x + threadIdx.x;       // one float4 per thread
    if (i >= IN_CH * OUT_CH / 4) return;
    int flat = i * 4;
    int k   = flat / OUT_CH;
    int col = flat % OUT_CH;
    float4 v = *reinterpret_cast<const float4*>(w + flat);
    int s = k >> 5, j = k & 7, q = (k >> 3) & 3;
    float vv[4] = {v.x, v.y, v.z, v.w};
    #pragma unroll
    for (int c = 0; c < 4; ++c) {
        int cc = col + c;
        int t  = cc >> 4;
        int ln = (cc & 15) | (q << 4);
        wfrag[((s * 3 + t) * 64 + ln) * 8 + j] = (unsigned short)f2bf(vv[c]);
    }
}

// ---------------- Kernel 1 (merged): gemm blocks + hist blocks ----------------
static __device__ void gemm_body(char* smem, const float* __restrict__ f,
                                 const unsigned short* __restrict__ wfrag,
                                 unsigned short* __restrict__ xw) {
    short* sBl = reinterpret_cast<short*>(smem);

    int tid  = threadIdx.x;
    int lane = tid & 63;
    int wid  = tid >> 6;

    {
        const uint4* gw = reinterpret_cast<const uint4*>(wfrag);
        uint4*       sw = reinterpret_cast<uint4*>(smem);
        #pragma unroll
        for (int i = 0; i < BFRAG_SHORTS / 8 / 256; ++i)   // 12 iterations
            sw[i * 256 + tid] = gw[i * 256 + tid];
    }
    __syncthreads();

    int tile = blockIdx.x * 4 + wid;
    if (tile >= N_TILES) return;

    const bf16x8* sB = reinterpret_cast<const bf16x8*>(sBl);

    int row = tile * 16 + (lane & 15);
    const float* fp = f + (size_t)row * IN_CH + ((lane >> 4) << 3);

    f32x4 acc0 = {0.f, 0.f, 0.f, 0.f};
    f32x4 acc1 = {0.f, 0.f, 0.f, 0.f};
    f32x4 acc2 = {0.f, 0.f, 0.f, 0.f};

    float4 a0[2], a1[2];
    a0[0] = *reinterpret_cast<const float4*>(fp);
    a1[0] = *reinterpret_cast<const float4*>(fp + 4);

    #pragma unroll
    for (int s = 0; s < 16; ++s) {
        const int cb = s & 1, nb = cb ^ 1;
        if (s + 1 < 16) {                                  // prefetch next K-step
            a0[nb] = *reinterpret_cast<const float4*>(fp + (s + 1) * 32);
            a1[nb] = *reinterpret_cast<const float4*>(fp + (s + 1) * 32 + 4);
        }
        bf16x8 a;
        a[0] = f2bf(a0[cb].x); a[1] = f2bf(a0[cb].y);
        a[2] = f2bf(a0[cb].z); a[3] = f2bf(a0[cb].w);
        a[4] = f2bf(a1[cb].x); a[5] = f2bf(a1[cb].y);
        a[6] = f2bf(a1[cb].z); a[7] = f2bf(a1[cb].w);
        bf16x8 b0 = sB[(s * 3 + 0) * 64 + lane];
        bf16x8 b1 = sB[(s * 3 + 1) * 64 + lane];
        bf16x8 b2 = sB[(s * 3 + 2) * 64 + lane];
        acc0 = __builtin_amdgcn_mfma_f32_16x16x32_bf16(a, b0, acc0, 0, 0, 0);
        acc1 = __builtin_amdgcn_mfma_f32_16x16x32_bf16(a, b1, acc1, 0, 0, 0);
        acc2 = __builtin_amdgcn_mfma_f32_16x16x32_bf16(a, b2, acc2, 0, 0, 0);
    }

    unsigned short* orow = xw + (size_t)tile * 16 * XW_LD;
    int c  = lane & 15;
    int r0 = (lane >> 4) * 4;
    #pragma unroll
    for (int r = 0; r < 4; ++r) {
        orow[(size_t)(r0 + r) * XW_LD +  0 + c] = (unsigned short)f2bf(acc0[r]);
        orow[(size_t)(r0 + r) * XW_LD + 16 + c] = (unsigned short)f2bf(acc1[r]);
        orow[(size_t)(r0 + r) * XW_LD + 32 + c] = (unsigned short)f2bf(acc2[r]);
    }
}

static __device__ void hist_body(char* smem, int bid, const int* __restrict__ dst,
                                 int* __restrict__ counts) {
    int* hc = reinterpret_cast<int*>(smem);
    for (int i = threadIdx.x; i < NB; i += 256) hc[i] = 0;
    __syncthreads();
    for (int e = bid * 256 + threadIdx.x; e < N_EDGES; e += HIST_BLOCKS * 256)
        atomicAdd(&hc[dst[e] >> BSHIFT], 1);
    __syncthreads();
    for (int i = threadIdx.x; i < NB; i += 256)
        if (hc[i]) atomicAdd(&counts[i], hc[i]);
}

__global__ __launch_bounds__(256) void gemm_hist(const float* __restrict__ f,
                                                 const unsigned short* __restrict__ wfrag,
                                                 unsigned short* __restrict__ xw,
                                                 const int* __restrict__ dst,
                                                 int* __restrict__ counts) {
    __shared__ __align__(16) char smem[BFRAG_SHORTS * 2];   // 48 KB union
    if (blockIdx.x < GEMM_BLOCKS) gemm_body(smem, f, wfrag, xw);
    else                          hist_body(smem, blockIdx.x - GEMM_BLOCKS, dst, counts);
}

// ---------------- Kernel 3: exclusive scan over NB buckets (1 block, 2/thread) ----------------
__global__ __launch_bounds__(1024) void bucket_scan(const int* __restrict__ counts,
                                                    int* __restrict__ base,
                                                    int* __restrict__ cursor) {
    __shared__ int sdata[1024];
    int t = threadIdx.x;
    int i0 = 2 * t, i1 = 2 * t + 1;
    int v0 = (i0 < NB) ? counts[i0] : 0;
    int v1 = (i1 < NB) ? counts[i1] : 0;
    int s = v0 + v1;
    sdata[t] = s;
    __syncthreads();
    for (int d = 1; d < 1024; d <<= 1) {
        int x = (t >= d) ? sdata[t - d] : 0;
        __syncthreads();
        sdata[t] += x;
        __syncthreads();
    }
    int excl = sdata[t] - s;
    if (i0 < NB) { base[i0] = excl;      cursor[i0] = excl; }
    if (i1 < NB) { base[i1] = excl + v0; cursor[i1] = excl + v0; }
}

// ---------------- Kernel 4: LDS-staged binning (coalesced scatter) ----------------
__global__ __launch_bounds__(512) void bin_edges(const int* __restrict__ src,
                                                 const int* __restrict__ dst,
                                                 const float* __restrict__ ew,
                                                 int* __restrict__ cursor,
                                                 int2* __restrict__ epack) {
    __shared__ int   hist[NB];
    __shared__ int   loff[NB];
    __shared__ int   gbase[NB];
    __shared__ int   ssum[512];
    __shared__ int2  buf[ETILE];      // 32 KB
    __shared__ short bkt[ETILE];      // 8 KB

    int tid = threadIdx.x;
    int tileStart = blockIdx.x * ETILE;
    int tileN = N_EDGES - tileStart; if (tileN > ETILE) tileN = ETILE;

    for (int i = tid; i < NB; i += 512) hist[i] = 0;
    __syncthreads();

    // pass A: ranks via LDS histogram (cache dst in registers)
    int rank[ETILE / 512];
    int dreg[ETILE / 512];
    #pragma unroll
    for (int k = 0; k < ETILE / 512; ++k) {
        int e = tileStart + k * 512 + tid;
        dreg[k] = (e < N_EDGES) ? dst[e] : 0;
        rank[k] = (e < N_EDGES) ? atomicAdd(&hist[dreg[k] >> BSHIFT], 1) : 0;
    }
    __syncthreads();

    // reserve global space per bucket
    for (int i = tid; i < NB; i += 512) {
        int c = hist[i];
        gbase[i] = c ? atomicAdd(&cursor[i], c) : 0;
    }

    // exclusive scan of hist -> loff (2 entries per thread, NB=782 <= 1024)
    int a0 = (2 * tid     < NB) ? hist[2 * tid]     : 0;
    int a1 = (2 * tid + 1 < NB) ? hist[2 * tid + 1] : 0;
    ssum[tid] = a0 + a1;
    __syncthreads();
    for (int d = 1; d < 512; d <<= 1) {
        int x = (tid >= d) ? ssum[tid - d] : 0;
        __syncthreads();
        ssum[tid] += x;
        __syncthreads();
    }
    int excl = ssum[tid] - (a0 + a1);
    if (2 * tid     < NB) loff[2 * tid]     = excl;
    if (2 * tid + 1 < NB) loff[2 * tid + 1] = excl + a0;
    __syncthreads();

    // pass B: stage edges into LDS in bucket order
    #pragma unroll
    for (int k = 0; k < ETILE / 512; ++k) {
        int e = tileStart + k * 512 + tid;
        if (e < N_EDGES) {
            int d = dreg[k];
            int b = d >> BSHIFT;
            int slot = loff[b] + rank[k];
            int2 p;
            p.x = (src[e] & 0xFFFF) | (d << 16);   // src 16b | full dst 16b
            p.y = __float_as_int(ew[e]);
            buf[slot] = p;
            bkt[slot] = (short)b;
        }
    }
    __syncthreads();

    // streaming writeout: consecutive slots -> consecutive global positions
    for (int idx = tid; idx < tileN; idx += 512) {
        int b = bkt[idx];
        epack[gbase[b] + idx - loff[b]] = buf[idx];
    }
}

// ---------------- Kernel 5: in-bucket sort by node (512 threads) ----------------
__global__ __launch_bounds__(512) void sort_bucket(const int* __restrict__ base,
                                                   const int* __restrict__ cursor,
                                                   int2* __restrict__ epack) {
    __shared__ int2  A[CAP];      // 22.5 KB
    __shared__ int2  B[CAP];      // 22.5 KB
    __shared__ short rk[CAP];     // 5.6 KB
    __shared__ int   hist[BNODES];
    __shared__ int   loff[BNODES];

    int b  = blockIdx.x;
    int lo = base[b], hi = cursor[b];
    int len = hi - lo;
    if (len <= 0 || len > CAP) return;   // oversize: leave unsorted (agg still correct)

    int tid = threadIdx.x;
    if (tid < BNODES) hist[tid] = 0;
    for (int i = tid; i < len; i += 512) A[i] = epack[lo + i];
    __syncthreads();

    for (int i = tid; i < len; i += 512) {
        int key = (((unsigned)A[i].x) >> 16) & (BNODES - 1);
        rk[i] = (short)atomicAdd(&hist[key], 1);
    }
    __syncthreads();

    if (tid < BNODES) {           // wave 0: exclusive scan of 64 counters
        int v = hist[tid];
        int s = v;
        #pragma unroll
        for (int d = 1; d < 64; d <<= 1) {
            int t = __shfl_up(s, d);
            if (tid >= d) s += t;
        }
        loff[tid] = s - v;
    }
    __syncthreads();

    for (int i = tid; i < len; i += 512) {
        int key = (((unsigned)A[i].x) >> 16) & (BNODES - 1);
        B[loff[key] + rk[i]] = A[i];
    }
    __syncthreads();

    for (int i = tid; i < len; i += 512) epack[lo + i] = B[i];
}

// ---------------- Kernel 6: segmented reduction over sorted edges ----------------
// 512-thread blocks (8 waves), one wave per 128-edge chunk, TWO independent
// half-wave streams; one dword gather = 2 bf16 channels, one line per edge;
// 8-deep double-buffered batches; run-boundary global fp32 atomic pairs.
__global__ __launch_bounds__(512) void seg_aggregate(const int2* __restrict__ epack,
                                                     const unsigned short* __restrict__ xw,
                                                     float* __restrict__ out) {
    int wv   = (blockIdx.x * blockDim.x + threadIdx.x) >> 6;
    int lane = threadIdx.x & 63;
    int base = wv * CHUNK;
    if (base >= N_EDGES) return;          // CHUNK divides N_EDGES exactly
    int h  = lane >> 5;                   // half: 0 -> even edges, 1 -> odd edges
    int cp = lane & 31;                   // channel pair (cp<24 real, rest pad)
    bool act = (cp < 24);

    int2 E0 = epack[base + lane];
    int2 E1 = epack[base + 64 + lane];

    float ax = 0.f, ay = 0.f;
    int cur = ((unsigned)__shfl(E0.x, h)) >> 16;

    int px[2][8]; float pw[2][8]; unsigned u[2][8];

    #pragma unroll
    for (int k = 0; k < 8; ++k) {
        int idx = ((2 * k) & 63) | h;
        px[0][k] = __shfl(E0.x, idx);
        pw[0][k] = __int_as_float(__shfl(E0.y, idx));
    }
    #pragma unroll
    for (int k = 0; k < 8; ++k)
        u[0][k] = *reinterpret_cast<const unsigned*>(
            xw + (size_t)(px[0][k] & 0xFFFF) * XW_LD + (cp << 1));

    #pragma unroll
    for (int j = 0; j < 8; ++j) {
        const int cb = j & 1, nb = cb ^ 1;
        if (j + 1 < 8) {
            #pragma unroll
            for (int k = 0; k < 8; ++k) {
                int t  = (j + 1) * 8 + k;
                int sx = (t < 32) ? E0.x : E1.x;
                int sy = (t < 32) ? E0.y : E1.y;
                int idx = ((2 * t) & 63) | h;
                px[nb][k] = __shfl(sx, idx);
                pw[nb][k] = __int_as_float(__shfl(sy, idx));
            }
            #pragma unroll
            for (int k = 0; k < 8; ++k)
                u[nb][k] = *reinterpret_cast<const unsigned*>(
                    xw + (size_t)(px[nb][k] & 0xFFFF) * XW_LD + (cp << 1));
        }
        #pragma unroll
        for (int k = 0; k < 8; ++k) {
            int node = ((unsigned)px[cb][k]) >> 16;
            if (node != cur) {
                if (act) {
                    atomicAdd(&out[(size_t)cur * OUT_CH + (cp << 1)    ], ax);
                    atomicAdd(&out[(size_t)cur * OUT_CH + (cp << 1) + 1], ay);
                }
                ax = 0.f; ay = 0.f; cur = node;
            }
            float    wf = pw[cb][k];
            unsigned uu = u[cb][k];
            ax = fmaf(wf, bf2f(uu & 0xFFFFu), ax);
            ay = fmaf(wf, bf2f(uu >> 16), ay);
        }
    }

    if (act) {
        atomicAdd(&out[(size_t)cur * OUT_CH + (cp << 1)    ], ax);
        atomicAdd(&out[(size_t)cur * OUT_CH + (cp << 1) + 1], ay);
    }
}

// ---------------- Kernel 7: bias + log-softmax, in place, wave per node ----------------
__global__ __launch_bounds__(256) void lsm_rows(float* __restrict__ z,
                                                const float* __restrict__ bias) {
    int node = (blockIdx.x * blockDim.x + threadIdx.x) >> 6;
    int lane = threadIdx.x & 63;
    if (node >= N_NODES) return;
    bool ch = (lane < OUT_CH);

    float v = ch ? (z[(size_t)node * OUT_CH + lane] + bias[lane]) : -INFINITY;
    float m = v;
    #pragma unroll
    for (int d = 32; d >= 1; d >>= 1) m = fmaxf(m, __shfl_xor(m, d));
    float e = ch ? expf(v - m) : 0.f;
    float s = e;
    #pragma unroll
    for (int d = 32; d >= 1; d >>= 1) s += __shfl_xor(s, d);
    float lse = m + logf(s);
    if (ch) z[(size_t)node * OUT_CH + lane] = v - lse;
}

extern "C" void kernel_launch(void* const* d_in, const int* in_sizes, int n_in,
                              void* d_out, int out_size, void* d_ws, size_t ws_size,
                              hipStream_t stream) {
    const int*   edge_index = (const int*)d_in[0];
    const float* features   = (const float*)d_in[1];
    const float* eweights   = (const float*)d_in[2];
    const float* weight     = (const float*)d_in[3];
    const float* bias       = (const float*)d_in[4];

    const int* src = edge_index;            // edge_index[0, :]
    const int* dst = edge_index + N_EDGES;  // edge_index[1, :]

    float* out = (float*)d_out;

    // Workspace layout (bytes):
    //   xw (bf16, LD=64) @ 0 : 50000*64*2 = 6,400,000
    //   counts  @ 9,600,000 : NB*4
    //   base    @ 9,616,000 : NB*4
    //   cursor  @ 9,632,000 : NB*4
    //   epack   @ 9,648,000 : 12,800,000   (ends 22,448,000)
    //   wfrag   @ 22,448,000 : 49,152
    char* ws = (char*)d_ws;
    unsigned short* xw    = (unsigned short*)(ws + 0);
    int*   counts = (int*)  (ws + 9600000);
    int*   base   = (int*)  (ws + 9616000);
    int*   cursor = (int*)  (ws + 9632000);
    int2*  epack  = (int2*) (ws + 9648000);
    unsigned short* wfrag = (unsigned short*)(ws + 22448000);

    hipMemsetAsync(counts, 0, NB * sizeof(int), stream);
    hipMemsetAsync(d_out, 0, (size_t)N_NODES * OUT_CH * sizeof(float), stream);

    // 0) pre-format B fragments (once per launch)
    prep_bfrag<<<(IN_CH * OUT_CH / 4 + 255) / 256, 256, 0, stream>>>(weight, wfrag);

    // 1) gemm (bf16 MFMA) and dst-histogram, concurrent in one launch
    gemm_hist<<<GEMM_BLOCKS + HIST_BLOCKS, 256, 0, stream>>>(features, wfrag, xw,
                                                             dst, counts);

    // 2) scan + bucket binning (coarse, write-coalesced) + in-bucket sort
    bucket_scan<<<1, 1024, 0, stream>>>(counts, base, cursor);
    bin_edges<<<(N_EDGES + ETILE - 1) / ETILE, 512, 0, stream>>>(src, dst, eweights,
                                                                 cursor, epack);
    sort_bucket<<<NB, 512, 0, stream>>>(base, cursor, epack);

    // 3) segmented reduction (512-thread blocks, wave per 128-edge chunk)
    {
        int nWaves  = N_EDGES / CHUNK;                 // 12500
        int nBlocks = (nWaves + 7) / 8;                // 1563
        seg_aggregate<<<nBlocks, 512, 0, stream>>>(epack, xw, out);
    }
    // 4) bias + log-softmax
    lsm_rows<<<(N_NODES + 3) / 4, 256, 0, stream>>>(out, bias);
}

// Round 22
// 144.245 us; speedup vs baseline: 3.7025x; 1.0112x over previous
//
#include <hip/hip_runtime.h>
#include <math.h>

#define N_NODES 50000
#define N_EDGES 1600000
#define IN_CH   512
#define OUT_CH  48
#define XW_LD   64                   // xw row stride in ushorts -> 128B, one cache line
#define N_TILES (N_NODES / 16)       // 3125 row-tiles, exact

#define BSHIFT  6                    // 64 nodes per bucket
#define BNODES  64
#define NB      ((N_NODES + BNODES - 1) / BNODES)   // 782 buckets
#define ETILE   4096                 // edges per bin block (391 blocks)
#define CAP     2816                 // max edges per bucket handled by sort (mean 2046)
#define CHUNK   64                   // edges per wave in seg_aggregate (divides N_EDGES)

#define BFRAG_SHORTS (16 * 3 * 64 * 8)   // 24576 shorts = 48 KB fragment image of B

#define PREP_BLOCKS 24               // 6144 threads / 256
#define HIST_BLOCKS 256
#define GEMMB_BLOCKS ((N_TILES + 7) / 8)            // 391 (8 tiles per 512-thr block)
#define BIN_BLOCKS   ((N_EDGES + ETILE - 1) / ETILE) // 391

typedef __attribute__((ext_vector_type(8))) short bf16x8;
typedef __attribute__((ext_vector_type(4))) float f32x4;

// fp32 -> bf16 (round-to-nearest-even), branch-free
static __device__ inline short f2bf(float x) {
    union { float f; unsigned u; } in; in.f = x;
    unsigned r = in.u + 0x7fffu + ((in.u >> 16) & 1u);
    return (short)(r >> 16);
}
static __device__ inline float bf2f(unsigned v16) {
    union { unsigned u; float f; } o; o.u = v16 << 16; return o.f;
}

// ---------------- Kernel A (merged): prep_bfrag blocks + hist blocks ----------------
static __device__ void prep_body(const float* __restrict__ w,
                                 unsigned short* __restrict__ wfrag) {
    int i = blockIdx.x * 256 + threadIdx.x;              // one float4 per thread
    if (i >= IN_CH * OUT_CH / 4) return;
    int flat = i * 4;
    int k   = flat / OUT_CH;
    int col = flat % OUT_CH;
    float4 v = *reinterpret_cast<const float4*>(w + flat);
    int s = k >> 5, j = k & 7, q = (k >> 3) & 3;
    float vv[4] = {v.x, v.y, v.z, v.w};
    #pragma unroll
    for (int c = 0; c < 4; ++c) {
        int cc = col + c;
        int t  = cc >> 4;
        int ln = (cc & 15) | (q << 4);
        wfrag[((s * 3 + t) * 64 + ln) * 8 + j] = (unsigned short)f2bf(vv[c]);
    }
}

__global__ __launch_bounds__(256) void prep_hist(const float* __restrict__ w,
                                                 unsigned short* __restrict__ wfrag,
                                                 const int* __restrict__ dst,
                                                 int* __restrict__ counts) {
    __shared__ int hc[NB];
    if (blockIdx.x < PREP_BLOCKS) { prep_body(w, wfrag); return; }
    int bid = blockIdx.x - PREP_BLOCKS;
    for (int i = threadIdx.x; i < NB; i += 256) hc[i] = 0;
    __syncthreads();
    for (int e = bid * 256 + threadIdx.x; e < N_EDGES; e += HIST_BLOCKS * 256)
        atomicAdd(&hc[dst[e] >> BSHIFT], 1);
    __syncthreads();
    for (int i = threadIdx.x; i < NB; i += 256)
        if (hc[i]) atomicAdd(&counts[i], hc[i]);
}

// ---------------- Kernel: exclusive scan over NB buckets (1 block, 2/thread) ----------------
__global__ __launch_bounds__(1024) void bucket_scan(const int* __restrict__ counts,
                                                    int* __restrict__ base,
                                                    int* __restrict__ cursor) {
    __shared__ int sdata[1024];
    int t = threadIdx.x;
    int i0 = 2 * t, i1 = 2 * t + 1;
    int v0 = (i0 < NB) ? counts[i0] : 0;
    int v1 = (i1 < NB) ? counts[i1] : 0;
    int s = v0 + v1;
    sdata[t] = s;
    __syncthreads();
    for (int d = 1; d < 1024; d <<= 1) {
        int x = (t >= d) ? sdata[t - d] : 0;
        __syncthreads();
        sdata[t] += x;
        __syncthreads();
    }
    int excl = sdata[t] - s;
    if (i0 < NB) { base[i0] = excl;      cursor[i0] = excl; }
    if (i1 < NB) { base[i1] = excl + v0; cursor[i1] = excl + v0; }
}

// ---------------- Kernel B (merged): gemm blocks (8 tiles, 512 thr) + bin blocks ----------------
static __device__ void gemm_body512(char* smem, const float* __restrict__ f,
                                    const unsigned short* __restrict__ wfrag,
                                    unsigned short* __restrict__ xw) {
    short* sBl = reinterpret_cast<short*>(smem);

    int tid  = threadIdx.x;
    int lane = tid & 63;
    int wid  = tid >> 6;                                 // 8 waves

    {
        const uint4* gw = reinterpret_cast<const uint4*>(wfrag);
        uint4*       sw = reinterpret_cast<uint4*>(smem);
        #pragma unroll
        for (int i = 0; i < BFRAG_SHORTS / 8 / 512; ++i)   // 6 iterations
            sw[i * 512 + tid] = gw[i * 512 + tid];
    }
    __syncthreads();

    int tile = blockIdx.x * 8 + wid;
    if (tile >= N_TILES) return;

    const bf16x8* sB = reinterpret_cast<const bf16x8*>(sBl);

    int row = tile * 16 + (lane & 15);
    const float* fp = f + (size_t)row * IN_CH + ((lane >> 4) << 3);

    f32x4 acc0 = {0.f, 0.f, 0.f, 0.f};
    f32x4 acc1 = {0.f, 0.f, 0.f, 0.f};
    f32x4 acc2 = {0.f, 0.f, 0.f, 0.f};

    float4 a0[2], a1[2];
    a0[0] = *reinterpret_cast<const float4*>(fp);
    a1[0] = *reinterpret_cast<const float4*>(fp + 4);

    #pragma unroll
    for (int s = 0; s < 16; ++s) {
        const int cb = s & 1, nb = cb ^ 1;
        if (s + 1 < 16) {                                  // prefetch next K-step
            a0[nb] = *reinterpret_cast<const float4*>(fp + (s + 1) * 32);
            a1[nb] = *reinterpret_cast<const float4*>(fp + (s + 1) * 32 + 4);
        }
        bf16x8 a;
        a[0] = f2bf(a0[cb].x); a[1] = f2bf(a0[cb].y);
        a[2] = f2bf(a0[cb].z); a[3] = f2bf(a0[cb].w);
        a[4] = f2bf(a1[cb].x); a[5] = f2bf(a1[cb].y);
        a[6] = f2bf(a1[cb].z); a[7] = f2bf(a1[cb].w);
        bf16x8 b0 = sB[(s * 3 + 0) * 64 + lane];
        bf16x8 b1 = sB[(s * 3 + 1) * 64 + lane];
        bf16x8 b2 = sB[(s * 3 + 2) * 64 + lane];
        acc0 = __builtin_amdgcn_mfma_f32_16x16x32_bf16(a, b0, acc0, 0, 0, 0);
        acc1 = __builtin_amdgcn_mfma_f32_16x16x32_bf16(a, b1, acc1, 0, 0, 0);
        acc2 = __builtin_amdgcn_mfma_f32_16x16x32_bf16(a, b2, acc2, 0, 0, 0);
    }

    unsigned short* orow = xw + (size_t)tile * 16 * XW_LD;
    int c  = lane & 15;
    int r0 = (lane >> 4) * 4;
    #pragma unroll
    for (int r = 0; r < 4; ++r) {
        orow[(size_t)(r0 + r) * XW_LD +  0 + c] = (unsigned short)f2bf(acc0[r]);
        orow[(size_t)(r0 + r) * XW_LD + 16 + c] = (unsigned short)f2bf(acc1[r]);
        orow[(size_t)(r0 + r) * XW_LD + 32 + c] = (unsigned short)f2bf(acc2[r]);
    }
}

static __device__ void bin_body(char* smem, int bid, const int* __restrict__ src,
                                const int* __restrict__ dst, const float* __restrict__ ew,
                                int* __restrict__ cursor, int2* __restrict__ epack) {
    // smem layout (bytes): hist@0 (3128), loff@3200 (3128), gbase@6400 (3128),
    // ssum@9600 (2048), buf@11648 (32768), bkt@44416 (8192) -> 52608 total
    int*   hist  = reinterpret_cast<int*>(smem);
    int*   loff  = reinterpret_cast<int*>(smem + 3200);
    int*   gbase = reinterpret_cast<int*>(smem + 6400);
    int*   ssum  = reinterpret_cast<int*>(smem + 9600);
    int2*  buf   = reinterpret_cast<int2*>(smem + 11648);
    short* bkt   = reinterpret_cast<short*>(smem + 44416);

    int tid = threadIdx.x;
    int tileStart = bid * ETILE;
    int tileN = N_EDGES - tileStart; if (tileN > ETILE) tileN = ETILE;

    for (int i = tid; i < NB; i += 512) hist[i] = 0;
    __syncthreads();

    // pass A: ranks via LDS histogram (cache dst in registers)
    int rank[ETILE / 512];
    int dreg[ETILE / 512];
    #pragma unroll
    for (int k = 0; k < ETILE / 512; ++k) {
        int e = tileStart + k * 512 + tid;
        dreg[k] = (e < N_EDGES) ? dst[e] : 0;
        rank[k] = (e < N_EDGES) ? atomicAdd(&hist[dreg[k] >> BSHIFT], 1) : 0;
    }
    __syncthreads();

    // reserve global space per bucket
    for (int i = tid; i < NB; i += 512) {
        int c = hist[i];
        gbase[i] = c ? atomicAdd(&cursor[i], c) : 0;
    }

    // exclusive scan of hist -> loff (2 entries per thread, NB=782 <= 1024)
    int a0 = (2 * tid     < NB) ? hist[2 * tid]     : 0;
    int a1 = (2 * tid + 1 < NB) ? hist[2 * tid + 1] : 0;
    ssum[tid] = a0 + a1;
    __syncthreads();
    for (int d = 1; d < 512; d <<= 1) {
        int x = (tid >= d) ? ssum[tid - d] : 0;
        __syncthreads();
        ssum[tid] += x;
        __syncthreads();
    }
    int excl = ssum[tid] - (a0 + a1);
    if (2 * tid     < NB) loff[2 * tid]     = excl;
    if (2 * tid + 1 < NB) loff[2 * tid + 1] = excl + a0;
    __syncthreads();

    // pass B: stage edges into LDS in bucket order
    #pragma unroll
    for (int k = 0; k < ETILE / 512; ++k) {
        int e = tileStart + k * 512 + tid;
        if (e < N_EDGES) {
            int d = dreg[k];
            int b = d >> BSHIFT;
            int slot = loff[b] + rank[k];
            int2 p;
            p.x = (src[e] & 0xFFFF) | (d << 16);   // src 16b | full dst 16b
            p.y = __float_as_int(ew[e]);
            buf[slot] = p;
            bkt[slot] = (short)b;
        }
    }
    __syncthreads();

    // streaming writeout: consecutive slots -> consecutive global positions
    for (int idx = tid; idx < tileN; idx += 512) {
        int b = bkt[idx];
        epack[gbase[b] + idx - loff[b]] = buf[idx];
    }
}

__global__ __launch_bounds__(512) void gemm_bin(const float* __restrict__ f,
                                                const unsigned short* __restrict__ wfrag,
                                                unsigned short* __restrict__ xw,
                                                const int* __restrict__ src,
                                                const int* __restrict__ dst,
                                                const float* __restrict__ ew,
                                                int* __restrict__ cursor,
                                                int2* __restrict__ epack) {
    __shared__ __align__(16) char smem[52608];   // union: gemm 48KB | bin 51.4KB
    if (blockIdx.x < GEMMB_BLOCKS) gemm_body512(smem, f, wfrag, xw);
    else bin_body(smem, blockIdx.x - GEMMB_BLOCKS, src, dst, ew, cursor, epack);
}

// ---------------- Kernel: in-bucket sort by node (512 threads) ----------------
__global__ __launch_bounds__(512) void sort_bucket(const int* __restrict__ base,
                                                   const int* __restrict__ cursor,
                                                   int2* __restrict__ epack) {
    __shared__ int2  A[CAP];      // 22.5 KB
    __shared__ int2  B[CAP];      // 22.5 KB
    __shared__ short rk[CAP];     // 5.6 KB
    __shared__ int   hist[BNODES];
    __shared__ int   loff[BNODES];

    int b  = blockIdx.x;
    int lo = base[b], hi = cursor[b];
    int len = hi - lo;
    if (len <= 0 || len > CAP) return;   // oversize: leave unsorted (agg still correct)

    int tid = threadIdx.x;
    if (tid < BNODES) hist[tid] = 0;
    for (int i = tid; i < len; i += 512) A[i] = epack[lo + i];
    __syncthreads();

    for (int i = tid; i < len; i += 512) {
        int key = (((unsigned)A[i].x) >> 16) & (BNODES - 1);
        rk[i] = (short)atomicAdd(&hist[key], 1);
    }
    __syncthreads();

    if (tid < BNODES) {           // wave 0: exclusive scan of 64 counters
        int v = hist[tid];
        int s = v;
        #pragma unroll
        for (int d = 1; d < 64; d <<= 1) {
            int t = __shfl_up(s, d);
            if (tid >= d) s += t;
        }
        loff[tid] = s - v;
    }
    __syncthreads();

    for (int i = tid; i < len; i += 512) {
        int key = (((unsigned)A[i].x) >> 16) & (BNODES - 1);
        B[loff[key] + rk[i]] = A[i];
    }
    __syncthreads();

    for (int i = tid; i < len; i += 512) epack[lo + i] = B[i];
}

// ---------------- Kernel: segmented reduction over sorted edges (CHUNK=64) ----------------
// One wave per 64-edge chunk (25000 waves), TWO independent half-wave streams:
// half h = lane>=32 processes edges base+2t+h (t=0..31); cp = lane&31 is the
// channel pair (cp<24 real). One dword gather = 2 bf16 channels, one line per
// edge; 4 batches of 8, double-buffered (compile-time indices). Run-boundary
// flush: global fp32 atomic pairs (rare, sorted order).
__global__ __launch_bounds__(512) void seg_aggregate(const int2* __restrict__ epack,
                                                     const unsigned short* __restrict__ xw,
                                                     float* __restrict__ out) {
    int wv   = (blockIdx.x * blockDim.x + threadIdx.x) >> 6;
    int lane = threadIdx.x & 63;
    int base = wv * CHUNK;
    if (base >= N_EDGES) return;          // CHUNK divides N_EDGES exactly
    int h  = lane >> 5;                   // half: 0 -> even edges, 1 -> odd edges
    int cp = lane & 31;                   // channel pair (cp<24 real, rest pad)
    bool act = (cp < 24);

    int2 E0 = epack[base + lane];         // 64 edges in 64 lanes

    float ax = 0.f, ay = 0.f;
    int cur = ((unsigned)__shfl(E0.x, h)) >> 16;

    int px[2][8]; float pw[2][8]; unsigned u[2][8];

    #pragma unroll
    for (int k = 0; k < 8; ++k) {
        int idx = (2 * k) | h;            // edge 2k+h
        px[0][k] = __shfl(E0.x, idx);
        pw[0][k] = __int_as_float(__shfl(E0.y, idx));
    }
    #pragma unroll
    for (int k = 0; k < 8; ++k)
        u[0][k] = *reinterpret_cast<const unsigned*>(
            xw + (size_t)(px[0][k] & 0xFFFF) * XW_LD + (cp << 1));

    #pragma unroll
    for (int j = 0; j < 4; ++j) {         // 4 batches x 8 steps = 32 steps (64 edges)
        const int cb = j & 1, nb = cb ^ 1;
        if (j + 1 < 4) {
            #pragma unroll
            for (int k = 0; k < 8; ++k) {
                int t  = (j + 1) * 8 + k;
                int idx = (2 * t) | h;
                px[nb][k] = __shfl(E0.x, idx);
                pw[nb][k] = __int_as_float(__shfl(E0.y, idx));
            }
            #pragma unroll
            for (int k = 0; k < 8; ++k)
                u[nb][k] = *reinterpret_cast<const unsigned*>(
                    xw + (size_t)(px[nb][k] & 0xFFFF) * XW_LD + (cp << 1));
        }
        #pragma unroll
        for (int k = 0; k < 8; ++k) {
            int node = ((unsigned)px[cb][k]) >> 16;
            if (node != cur) {
                if (act) {
                    atomicAdd(&out[(size_t)cur * OUT_CH + (cp << 1)    ], ax);
                    atomicAdd(&out[(size_t)cur * OUT_CH + (cp << 1) + 1], ay);
                }
                ax = 0.f; ay = 0.f; cur = node;
            }
            float    wf = pw[cb][k];
            unsigned uu = u[cb][k];
            ax = fmaf(wf, bf2f(uu & 0xFFFFu), ax);
            ay = fmaf(wf, bf2f(uu >> 16), ay);
        }
    }

    if (act) {
        atomicAdd(&out[(size_t)cur * OUT_CH + (cp << 1)    ], ax);
        atomicAdd(&out[(size_t)cur * OUT_CH + (cp << 1) + 1], ay);
    }
}

// ---------------- Kernel: bias + log-softmax, in place, wave per node ----------------
__global__ __launch_bounds__(256) void lsm_rows(float* __restrict__ z,
                                                const float* __restrict__ bias) {
    int node = (blockIdx.x * blockDim.x + threadIdx.x) >> 6;
    int lane = threadIdx.x & 63;
    if (node >= N_NODES) return;
    bool ch = (lane < OUT_CH);

    float v = ch ? (z[(size_t)node * OUT_CH + lane] + bias[lane]) : -INFINITY;
    float m = v;
    #pragma unroll
    for (int d = 32; d >= 1; d >>= 1) m = fmaxf(m, __shfl_xor(m, d));
    float e = ch ? expf(v - m) : 0.f;
    float s = e;
    #pragma unroll
    for (int d = 32; d >= 1; d >>= 1) s += __shfl_xor(s, d);
    float lse = m + logf(s);
    if (ch) z[(size_t)node * OUT_CH + lane] = v - lse;
}

extern "C" void kernel_launch(void* const* d_in, const int* in_sizes, int n_in,
                              void* d_out, int out_size, void* d_ws, size_t ws_size,
                              hipStream_t stream) {
    const int*   edge_index = (const int*)d_in[0];
    const float* features   = (const float*)d_in[1];
    const float* eweights   = (const float*)d_in[2];
    const float* weight     = (const float*)d_in[3];
    const float* bias       = (const float*)d_in[4];

    const int* src = edge_index;            // edge_index[0, :]
    const int* dst = edge_index + N_EDGES;  // edge_index[1, :]

    float* out = (float*)d_out;

    // Workspace layout (bytes):
    //   xw (bf16, LD=64) @ 0 : 50000*64*2 = 6,400,000
    //   counts  @ 9,600,000 : NB*4
    //   base    @ 9,616,000 : NB*4
    //   cursor  @ 9,632,000 : NB*4
    //   epack   @ 9,648,000 : 12,800,000   (ends 22,448,000)
    //   wfrag   @ 22,448,000 : 49,152
    char* ws = (char*)d_ws;
    unsigned short* xw    = (unsigned short*)(ws + 0);
    int*   counts = (int*)  (ws + 9600000);
    int*   base   = (int*)  (ws + 9616000);
    int*   cursor = (int*)  (ws + 9632000);
    int2*  epack  = (int2*) (ws + 9648000);
    unsigned short* wfrag = (unsigned short*)(ws + 22448000);

    hipMemsetAsync(counts, 0, NB * sizeof(int), stream);
    hipMemsetAsync(d_out, 0, (size_t)N_NODES * OUT_CH * sizeof(float), stream);

    // A) prep_bfrag and dst-histogram, concurrent in one launch
    prep_hist<<<PREP_BLOCKS + HIST_BLOCKS, 256, 0, stream>>>(weight, wfrag, dst, counts);

    // B) scan, then gemm (bf16 MFMA) and bucket binning concurrent in one launch
    bucket_scan<<<1, 1024, 0, stream>>>(counts, base, cursor);
    gemm_bin<<<GEMMB_BLOCKS + BIN_BLOCKS, 512, 0, stream>>>(features, wfrag, xw,
                                                            src, dst, eweights,
                                                            cursor, epack);

    // C) in-bucket sort
    sort_bucket<<<NB, 512, 0, stream>>>(base, cursor, epack);

    // D) segmented reduction (wave per 64-edge chunk, 25000 waves)
    {
        int nWaves  = N_EDGES / CHUNK;                 // 25000
        int nBlocks = (nWaves + 7) / 8;                // 3125
        seg_aggregate<<<nBlocks, 512, 0, stream>>>(epack, xw, out);
    }
    // E) bias + log-softmax
    lsm_rows<<<(N_NODES + 3) / 4, 256, 0, stream>>>(out, bias);
}

// Round 23
// 128.441 us; speedup vs baseline: 4.1581x; 1.1230x over previous
//
#include <hip/hip_runtime.h>
#include <math.h>

#define N_NODES 50000
#define N_EDGES 1600000
#define IN_CH   512
#define OUT_CH  48
#define XW_LD   64                   // xw row stride in ushorts -> 128B, one cache line
#define N_TILES (N_NODES / 16)       // 3125 row-tiles, exact

#define BSHIFT  6                    // 64 nodes per bucket
#define BNODES  64
#define NB      ((N_NODES + BNODES - 1) / BNODES)   // 782 buckets
#define ETILE   4096                 // edges per bin block (391 blocks)
#define CAP     2816                 // max edges per bucket handled by sort (mean 2046)
#define CHUNK   128                  // edges per wave in seg_aggregate (divides N_EDGES)

#define BFRAG_SHORTS (16 * 3 * 64 * 8)   // 24576 shorts = 48 KB fragment image of B

#define PREP_BLOCKS 24               // 6144 threads / 256
#define HIST_BLOCKS 256
#define GEMMB_BLOCKS ((N_TILES + 7) / 8)            // 391 (8 tiles per 512-thr block)
#define BIN_BLOCKS   ((N_EDGES + ETILE - 1) / ETILE) // 391

typedef __attribute__((ext_vector_type(8))) short bf16x8;
typedef __attribute__((ext_vector_type(4))) float f32x4;

// fp32 -> bf16 (round-to-nearest-even), branch-free
static __device__ inline short f2bf(float x) {
    union { float f; unsigned u; } in; in.f = x;
    unsigned r = in.u + 0x7fffu + ((in.u >> 16) & 1u);
    return (short)(r >> 16);
}
static __device__ inline float bf2f(unsigned v16) {
    union { unsigned u; float f; } o; o.u = v16 << 16; return o.f;
}

// ---------------- Kernel A (merged): prep_bfrag blocks + hist blocks ----------------
static __device__ void prep_body(const float* __restrict__ w,
                                 unsigned short* __restrict__ wfrag) {
    int i = blockIdx.x * 256 + threadIdx.x;              // one float4 per thread
    if (i >= IN_CH * OUT_CH / 4) return;
    int flat = i * 4;
    int k   = flat / OUT_CH;
    int col = flat % OUT_CH;
    float4 v = *reinterpret_cast<const float4*>(w + flat);
    int s = k >> 5, j = k & 7, q = (k >> 3) & 3;
    float vv[4] = {v.x, v.y, v.z, v.w};
    #pragma unroll
    for (int c = 0; c < 4; ++c) {
        int cc = col + c;
        int t  = cc >> 4;
        int ln = (cc & 15) | (q << 4);
        wfrag[((s * 3 + t) * 64 + ln) * 8 + j] = (unsigned short)f2bf(vv[c]);
    }
}

__global__ __launch_bounds__(256) void prep_hist(const float* __restrict__ w,
                                                 unsigned short* __restrict__ wfrag,
                                                 const int* __restrict__ dst,
                                                 int* __restrict__ counts) {
    __shared__ int hc[NB];
    if (blockIdx.x < PREP_BLOCKS) { prep_body(w, wfrag); return; }
    int bid = blockIdx.x - PREP_BLOCKS;
    for (int i = threadIdx.x; i < NB; i += 256) hc[i] = 0;
    __syncthreads();
    for (int e = bid * 256 + threadIdx.x; e < N_EDGES; e += HIST_BLOCKS * 256)
        atomicAdd(&hc[dst[e] >> BSHIFT], 1);
    __syncthreads();
    for (int i = threadIdx.x; i < NB; i += 256)
        if (hc[i]) atomicAdd(&counts[i], hc[i]);
}

// ---------------- Kernel: exclusive scan over NB buckets (1 block, 2/thread) ----------------
__global__ __launch_bounds__(1024) void bucket_scan(const int* __restrict__ counts,
                                                    int* __restrict__ base,
                                                    int* __restrict__ cursor) {
    __shared__ int sdata[1024];
    int t = threadIdx.x;
    int i0 = 2 * t, i1 = 2 * t + 1;
    int v0 = (i0 < NB) ? counts[i0] : 0;
    int v1 = (i1 < NB) ? counts[i1] : 0;
    int s = v0 + v1;
    sdata[t] = s;
    __syncthreads();
    for (int d = 1; d < 1024; d <<= 1) {
        int x = (t >= d) ? sdata[t - d] : 0;
        __syncthreads();
        sdata[t] += x;
        __syncthreads();
    }
    int excl = sdata[t] - s;
    if (i0 < NB) { base[i0] = excl;      cursor[i0] = excl; }
    if (i1 < NB) { base[i1] = excl + v0; cursor[i1] = excl + v0; }
}

// ---------------- Kernel B (merged): gemm blocks (8 tiles, 512 thr) + bin blocks ----------------
static __device__ void gemm_body512(char* smem, const float* __restrict__ f,
                                    const unsigned short* __restrict__ wfrag,
                                    unsigned short* __restrict__ xw) {
    short* sBl = reinterpret_cast<short*>(smem);

    int tid  = threadIdx.x;
    int lane = tid & 63;
    int wid  = tid >> 6;                                 // 8 waves

    {
        const uint4* gw = reinterpret_cast<const uint4*>(wfrag);
        uint4*       sw = reinterpret_cast<uint4*>(smem);
        #pragma unroll
        for (int i = 0; i < BFRAG_SHORTS / 8 / 512; ++i)   // 6 iterations
            sw[i * 512 + tid] = gw[i * 512 + tid];
    }
    __syncthreads();

    int tile = blockIdx.x * 8 + wid;
    if (tile >= N_TILES) return;

    const bf16x8* sB = reinterpret_cast<const bf16x8*>(sBl);

    int row = tile * 16 + (lane & 15);
    const float* fp = f + (size_t)row * IN_CH + ((lane >> 4) << 3);

    f32x4 acc0 = {0.f, 0.f, 0.f, 0.f};
    f32x4 acc1 = {0.f, 0.f, 0.f, 0.f};
    f32x4 acc2 = {0.f, 0.f, 0.f, 0.f};

    float4 a0[2], a1[2];
    a0[0] = *reinterpret_cast<const float4*>(fp);
    a1[0] = *reinterpret_cast<const float4*>(fp + 4);

    #pragma unroll
    for (int s = 0; s < 16; ++s) {
        const int cb = s & 1, nb = cb ^ 1;
        if (s + 1 < 16) {                                  // prefetch next K-step
            a0[nb] = *reinterpret_cast<const float4*>(fp + (s + 1) * 32);
            a1[nb] = *reinterpret_cast<const float4*>(fp + (s + 1) * 32 + 4);
        }
        bf16x8 a;
        a[0] = f2bf(a0[cb].x); a[1] = f2bf(a0[cb].y);
        a[2] = f2bf(a0[cb].z); a[3] = f2bf(a0[cb].w);
        a[4] = f2bf(a1[cb].x); a[5] = f2bf(a1[cb].y);
        a[6] = f2bf(a1[cb].z); a[7] = f2bf(a1[cb].w);
        bf16x8 b0 = sB[(s * 3 + 0) * 64 + lane];
        bf16x8 b1 = sB[(s * 3 + 1) * 64 + lane];
        bf16x8 b2 = sB[(s * 3 + 2) * 64 + lane];
        acc0 = __builtin_amdgcn_mfma_f32_16x16x32_bf16(a, b0, acc0, 0, 0, 0);
        acc1 = __builtin_amdgcn_mfma_f32_16x16x32_bf16(a, b1, acc1, 0, 0, 0);
        acc2 = __builtin_amdgcn_mfma_f32_16x16x32_bf16(a, b2, acc2, 0, 0, 0);
    }

    unsigned short* orow = xw + (size_t)tile * 16 * XW_LD;
    int c  = lane & 15;
    int r0 = (lane >> 4) * 4;
    #pragma unroll
    for (int r = 0; r < 4; ++r) {
        orow[(size_t)(r0 + r) * XW_LD +  0 + c] = (unsigned short)f2bf(acc0[r]);
        orow[(size_t)(r0 + r) * XW_LD + 16 + c] = (unsigned short)f2bf(acc1[r]);
        orow[(size_t)(r0 + r) * XW_LD + 32 + c] = (unsigned short)f2bf(acc2[r]);
    }
}

static __device__ void bin_body(char* smem, int bid, const int* __restrict__ src,
                                const int* __restrict__ dst, const float* __restrict__ ew,
                                int* __restrict__ cursor, int2* __restrict__ epack) {
    int*   hist  = reinterpret_cast<int*>(smem);
    int*   loff  = reinterpret_cast<int*>(smem + 3200);
    int*   gbase = reinterpret_cast<int*>(smem + 6400);
    int*   ssum  = reinterpret_cast<int*>(smem + 9600);
    int2*  buf   = reinterpret_cast<int2*>(smem + 11648);
    short* bkt   = reinterpret_cast<short*>(smem + 44416);

    int tid = threadIdx.x;
    int tileStart = bid * ETILE;
    int tileN = N_EDGES - tileStart; if (tileN > ETILE) tileN = ETILE;

    for (int i = tid; i < NB; i += 512) hist[i] = 0;
    __syncthreads();

    int rank[ETILE / 512];
    int dreg[ETILE / 512];
    #pragma unroll
    for (int k = 0; k < ETILE / 512; ++k) {
        int e = tileStart + k * 512 + tid;
        dreg[k] = (e < N_EDGES) ? dst[e] : 0;
        rank[k] = (e < N_EDGES) ? atomicAdd(&hist[dreg[k] >> BSHIFT], 1) : 0;
    }
    __syncthreads();

    for (int i = tid; i < NB; i += 512) {
        int c = hist[i];
        gbase[i] = c ? atomicAdd(&cursor[i], c) : 0;
    }

    int a0 = (2 * tid     < NB) ? hist[2 * tid]     : 0;
    int a1 = (2 * tid + 1 < NB) ? hist[2 * tid + 1] : 0;
    ssum[tid] = a0 + a1;
    __syncthreads();
    for (int d = 1; d < 512; d <<= 1) {
        int x = (tid >= d) ? ssum[tid - d] : 0;
        __syncthreads();
        ssum[tid] += x;
        __syncthreads();
    }
    int excl = ssum[tid] - (a0 + a1);
    if (2 * tid     < NB) loff[2 * tid]     = excl;
    if (2 * tid + 1 < NB) loff[2 * tid + 1] = excl + a0;
    __syncthreads();

    #pragma unroll
    for (int k = 0; k < ETILE / 512; ++k) {
        int e = tileStart + k * 512 + tid;
        if (e < N_EDGES) {
            int d = dreg[k];
            int b = d >> BSHIFT;
            int slot = loff[b] + rank[k];
            int2 p;
            p.x = (src[e] & 0xFFFF) | (d << 16);   // src 16b | full dst 16b
            p.y = __float_as_int(ew[e]);
            buf[slot] = p;
            bkt[slot] = (short)b;
        }
    }
    __syncthreads();

    for (int idx = tid; idx < tileN; idx += 512) {
        int b = bkt[idx];
        epack[gbase[b] + idx - loff[b]] = buf[idx];
    }
}

__global__ __launch_bounds__(512) void gemm_bin(const float* __restrict__ f,
                                                const unsigned short* __restrict__ wfrag,
                                                unsigned short* __restrict__ xw,
                                                const int* __restrict__ src,
                                                const int* __restrict__ dst,
                                                const float* __restrict__ ew,
                                                int* __restrict__ cursor,
                                                int2* __restrict__ epack) {
    __shared__ __align__(16) char smem[52608];   // union: gemm 48KB | bin 51.4KB
    if (blockIdx.x < GEMMB_BLOCKS) gemm_body512(smem, f, wfrag, xw);
    else bin_body(smem, blockIdx.x - GEMMB_BLOCKS, src, dst, ew, cursor, epack);
}

// ---------------- Kernel: in-bucket sort by node (512 threads) ----------------
__global__ __launch_bounds__(512) void sort_bucket(const int* __restrict__ base,
                                                   const int* __restrict__ cursor,
                                                   int2* __restrict__ epack) {
    __shared__ int2  A[CAP];      // 22.5 KB
    __shared__ int2  B[CAP];      // 22.5 KB
    __shared__ short rk[CAP];     // 5.6 KB
    __shared__ int   hist[BNODES];
    __shared__ int   loff[BNODES];

    int b  = blockIdx.x;
    int lo = base[b], hi = cursor[b];
    int len = hi - lo;
    if (len <= 0 || len > CAP) return;   // oversize: leave unsorted (agg still correct)

    int tid = threadIdx.x;
    if (tid < BNODES) hist[tid] = 0;
    for (int i = tid; i < len; i += 512) A[i] = epack[lo + i];
    __syncthreads();

    for (int i = tid; i < len; i += 512) {
        int key = (((unsigned)A[i].x) >> 16) & (BNODES - 1);
        rk[i] = (short)atomicAdd(&hist[key], 1);
    }
    __syncthreads();

    if (tid < BNODES) {           // wave 0: exclusive scan of 64 counters
        int v = hist[tid];
        int s = v;
        #pragma unroll
        for (int d = 1; d < 64; d <<= 1) {
            int t = __shfl_up(s, d);
            if (tid >= d) s += t;
        }
        loff[tid] = s - v;
    }
    __syncthreads();

    for (int i = tid; i < len; i += 512) {
        int key = (((unsigned)A[i].x) >> 16) & (BNODES - 1);
        B[loff[key] + rk[i]] = A[i];
    }
    __syncthreads();

    for (int i = tid; i < len; i += 512) epack[lo + i] = B[i];
}

// ---------------- Kernel: segmented reduction over sorted edges ----------------
// One wave per 128-edge chunk, TWO independent half-wave streams; one dword
// gather = 2 bf16 channels, one line per edge; 8-deep double-buffered batches.
// PAIR-SPLIT accumulation layout: low ushort channels at row positions 0..23,
// high ushort channels at 24..47 -> each flush atomic writes 24 CONSECUTIVE
// floats (1-2 lines vs 2 lines each for the old stride-2 comb).
__global__ __launch_bounds__(512) void seg_aggregate(const int2* __restrict__ epack,
                                                     const unsigned short* __restrict__ xw,
                                                     float* __restrict__ out) {
    int wv   = (blockIdx.x * blockDim.x + threadIdx.x) >> 6;
    int lane = threadIdx.x & 63;
    int base = wv * CHUNK;
    if (base >= N_EDGES) return;          // CHUNK divides N_EDGES exactly
    int h  = lane >> 5;                   // half: 0 -> even edges, 1 -> odd edges
    int cp = lane & 31;                   // channel pair (cp<24 real, rest pad)
    bool act = (cp < 24);

    int2 E0 = epack[base + lane];
    int2 E1 = epack[base + 64 + lane];

    float ax = 0.f, ay = 0.f;
    int cur = ((unsigned)__shfl(E0.x, h)) >> 16;

    int px[2][8]; float pw[2][8]; unsigned u[2][8];

    #pragma unroll
    for (int k = 0; k < 8; ++k) {
        int idx = ((2 * k) & 63) | h;
        px[0][k] = __shfl(E0.x, idx);
        pw[0][k] = __int_as_float(__shfl(E0.y, idx));
    }
    #pragma unroll
    for (int k = 0; k < 8; ++k)
        u[0][k] = *reinterpret_cast<const unsigned*>(
            xw + (size_t)(px[0][k] & 0xFFFF) * XW_LD + (cp << 1));

    #pragma unroll
    for (int j = 0; j < 8; ++j) {
        const int cb = j & 1, nb = cb ^ 1;
        if (j + 1 < 8) {
            #pragma unroll
            for (int k = 0; k < 8; ++k) {
                int t  = (j + 1) * 8 + k;
                int sx = (t < 32) ? E0.x : E1.x;
                int sy = (t < 32) ? E0.y : E1.y;
                int idx = ((2 * t) & 63) | h;
                px[nb][k] = __shfl(sx, idx);
                pw[nb][k] = __int_as_float(__shfl(sy, idx));
            }
            #pragma unroll
            for (int k = 0; k < 8; ++k)
                u[nb][k] = *reinterpret_cast<const unsigned*>(
                    xw + (size_t)(px[nb][k] & 0xFFFF) * XW_LD + (cp << 1));
        }
        #pragma unroll
        for (int k = 0; k < 8; ++k) {
            int node = ((unsigned)px[cb][k]) >> 16;
            if (node != cur) {
                if (act) {
                    atomicAdd(&out[(size_t)cur * OUT_CH + cp     ], ax);  // consecutive
                    atomicAdd(&out[(size_t)cur * OUT_CH + 24 + cp], ay);  // consecutive
                }
                ax = 0.f; ay = 0.f; cur = node;
            }
            float    wf = pw[cb][k];
            unsigned uu = u[cb][k];
            ax = fmaf(wf, bf2f(uu & 0xFFFFu), ax);
            ay = fmaf(wf, bf2f(uu >> 16), ay);
        }
    }

    if (act) {
        atomicAdd(&out[(size_t)cur * OUT_CH + cp     ], ax);
        atomicAdd(&out[(size_t)cur * OUT_CH + 24 + cp], ay);
    }
}

// ---------------- Kernel: bias + log-softmax, pair-split -> standard layout ----------------
// z is in pair-split layout: position c holds channel 2c (c<24), position 24+c
// holds channel 2c+1. Softmax is order-independent; write standard layout.
__global__ __launch_bounds__(256) void lsm_rows(float* __restrict__ z,
                                                const float* __restrict__ bias) {
    int node = (blockIdx.x * blockDim.x + threadIdx.x) >> 6;
    int lane = threadIdx.x & 63;
    if (node >= N_NODES) return;
    bool ch = (lane < OUT_CH);

    // lane = output channel; its value lives at pair-split position:
    int pos = (lane >> 1) + 24 * (lane & 1);
    float v = ch ? (z[(size_t)node * OUT_CH + pos] + bias[lane]) : -INFINITY;
    float m = v;
    #pragma unroll
    for (int d = 32; d >= 1; d >>= 1) m = fmaxf(m, __shfl_xor(m, d));
    float e = ch ? expf(v - m) : 0.f;
    float s = e;
    #pragma unroll
    for (int d = 32; d >= 1; d >>= 1) s += __shfl_xor(s, d);
    float lse = m + logf(s);
    __syncthreads();   // intra-block: all reads of this block's rows done before writes
    if (ch) z[(size_t)node * OUT_CH + lane] = v - lse;
}

extern "C" void kernel_launch(void* const* d_in, const int* in_sizes, int n_in,
                              void* d_out, int out_size, void* d_ws, size_t ws_size,
                              hipStream_t stream) {
    const int*   edge_index = (const int*)d_in[0];
    const float* features   = (const float*)d_in[1];
    const float* eweights   = (const float*)d_in[2];
    const float* weight     = (const float*)d_in[3];
    const float* bias       = (const float*)d_in[4];

    const int* src = edge_index;            // edge_index[0, :]
    const int* dst = edge_index + N_EDGES;  // edge_index[1, :]

    float* out = (float*)d_out;

    // Workspace layout (bytes):
    //   xw (bf16, LD=64) @ 0 : 50000*64*2 = 6,400,000
    //   counts  @ 9,600,000 : NB*4
    //   base    @ 9,616,000 : NB*4
    //   cursor  @ 9,632,000 : NB*4
    //   epack   @ 9,648,000 : 12,800,000   (ends 22,448,000)
    //   wfrag   @ 22,448,000 : 49,152
    char* ws = (char*)d_ws;
    unsigned short* xw    = (unsigned short*)(ws + 0);
    int*   counts = (int*)  (ws + 9600000);
    int*   base   = (int*)  (ws + 9616000);
    int*   cursor = (int*)  (ws + 9632000);
    int2*  epack  = (int2*) (ws + 9648000);
    unsigned short* wfrag = (unsigned short*)(ws + 22448000);

    hipMemsetAsync(counts, 0, NB * sizeof(int), stream);
    hipMemsetAsync(d_out, 0, (size_t)N_NODES * OUT_CH * sizeof(float), stream);

    // A) prep_bfrag and dst-histogram, concurrent in one launch
    prep_hist<<<PREP_BLOCKS + HIST_BLOCKS, 256, 0, stream>>>(weight, wfrag, dst, counts);

    // B) scan, then gemm (bf16 MFMA) and bucket binning concurrent in one launch
    bucket_scan<<<1, 1024, 0, stream>>>(counts, base, cursor);
    gemm_bin<<<GEMMB_BLOCKS + BIN_BLOCKS, 512, 0, stream>>>(features, wfrag, xw,
                                                            src, dst, eweights,
                                                            cursor, epack);

    // C) in-bucket sort
    sort_bucket<<<NB, 512, 0, stream>>>(base, cursor, epack);

    // D) segmented reduction (wave per 128-edge chunk, pair-split atomics)
    {
        int nWaves  = N_EDGES / CHUNK;                 // 12500
        int nBlocks = (nWaves + 7) / 8;                // 1563
        seg_aggregate<<<nBlocks, 512, 0, stream>>>(epack, xw, out);
    }
    // E) bias + log-softmax (reads pair-split, writes standard)
    lsm_rows<<<(N_NODES + 3) / 4, 256, 0, stream>>>(out, bias);
}